// Round 5
// baseline (324.300 us; speedup 1.0000x reference)
//
#include <hip/hip_runtime.h>
#include <stdint.h>
#include <type_traits>

typedef unsigned short u16;
typedef __attribute__((ext_vector_type(8))) short short8;
typedef __attribute__((ext_vector_type(4))) float f32x4;

#define MFMA16(a,b,c) __builtin_amdgcn_mfma_f32_16x16x32_bf16(a,b,c,0,0,0)

__device__ __forceinline__ u16 f2bf(float f){
  uint32_t u = __builtin_bit_cast(uint32_t, f);
  u += 0x7FFFu + ((u>>16)&1u);
  return (u16)(u>>16);
}
__device__ __forceinline__ float bf2f(u16 h){
  uint32_t u = ((uint32_t)h)<<16;
  return __builtin_bit_cast(float, u);
}

// ---------------- prep: cast x f32->bf16 (bid<8192) + all weight transposes ----------------
__global__ __launch_bounds__(256) void prep(const float* __restrict__ x, u16* __restrict__ xb,
    const float* __restrict__ Wq, const float* __restrict__ Wk, const float* __restrict__ Wv,
    const float* __restrict__ Wg, const float* __restrict__ Wo,
    u16* __restrict__ WcatT, u16* __restrict__ WoT){
  int bid = blockIdx.x;
  if (bid < 8192){
    int i = (bid*256 + threadIdx.x)*4;
    float4 v = *(const float4*)&x[i];
    uint2 u;
    u.x = (uint32_t)f2bf(v.x) | ((uint32_t)f2bf(v.y)<<16);
    u.y = (uint32_t)f2bf(v.z) | ((uint32_t)f2bf(v.w)<<16);
    *(uint2*)&xb[i] = u;
    return;
  }
  bid -= 8192;
  const float* src; u16* dst; int R, Cc, tc, tr;
  if (bid < 1024){        src=Wq; dst=WcatT;             R=1024; Cc=1024; int b=bid;      tc=(b&31)*32; tr=(b>>5)*32; }
  else if (bid < 2048){   src=Wk; dst=WcatT+1024*1024;   R=1024; Cc=1024; int b=bid-1024; tc=(b&31)*32; tr=(b>>5)*32; }
  else if (bid < 4096){   src=Wv; dst=WcatT+2048*1024;   R=1024; Cc=2048; int b=bid-2048; tc=(b&63)*32; tr=(b>>6)*32; }
  else if (bid < 6144){   src=Wg; dst=WcatT+4096*1024;   R=1024; Cc=2048; int b=bid-4096; tc=(b&63)*32; tr=(b>>6)*32; }
  else {                  src=Wo; dst=WoT;               R=2048; Cc=1024; int b=bid-6144; tc=(b&31)*32; tr=(b>>5)*32; }
  __shared__ float tile[32][33];
  int lr = threadIdx.x>>5, lc = threadIdx.x&31;
  #pragma unroll
  for (int p=0;p<4;p++)
    tile[lr+p*8][lc] = src[(size_t)(tr+lr+p*8)*Cc + tc + lc];
  __syncthreads();
  #pragma unroll
  for (int p=0;p<4;p++)
    dst[(size_t)(tc+lr+p*8)*R + tr + lc] = f2bf(tile[lc][lr+p*8]);
}

// =================================================================
// gemm1: Round 5 — 128x128 tile, the verified gemm2_nt K-loop structure
// (m97-class: 4 waves, acc[4][4]=64 acc regs, 48 KiB 3-buffer LDS,
// counted vmcnt). Rationale: the 256x256 kernel was occupancy-capped
// (acc[8][4]=128 regs -> 2 waves/SIMD AND 1 block/CU: every barrier
// idles the whole CU; MfmaUtil pinned ~26% across all schedule edits).
// 128x128 halves per-wave regs and LDS -> >=2 independent blocks/CU;
// cross-block overlap fills barrier/vmcnt stalls (m114/m97: ~900 TF).
// + XCD-aware swizzle (r4, FETCH-verified) + fused RoPE bf16 epilogue.
// =================================================================
__global__ __launch_bounds__(256) void gemm1_128(const u16* __restrict__ A,
    const u16* __restrict__ BT, u16* __restrict__ C){
  __shared__ u16 L[3*8192];           // 3 x (A 8KB | B 8KB) = 48 KiB
  // XCD swizzle: 3072 blocks = 8 XCDs x (8 bm x 48 bn). Per XCD: 8 A-panels
  // (2 MB) L2-resident all kernel; B-panel reused 8x per bn sweep.
  const int flat = blockIdx.y*48 + blockIdx.x;   // grid (48,64)
  const int xcd  = flat & 7, loc = flat >> 3;    // loc in [0,384)
  const int bm   = xcd*8 + (loc & 7);            // [0,64)
  const int bn   = loc >> 3;                     // [0,48)
  const int t = threadIdx.x;
  const int w = t>>6, l = t&63;
  const int wr = (w>>1)*64, wc = (w&1)*64;
  const int lr = l&15, lg = l>>4;
  const int srow = t>>2;
  const int gsw  = ((t&3) - (t>>3)) & 3;
  const int scol = gsw*8;
  const size_t aoff = (size_t)(bm*128 + srow)*1024 + scol;
  const size_t boff = (size_t)(bn*128 + srow)*1024 + scol;
  const int sdo = t*8;

  u16 *a0 = L,          *b0 = L + 4096;
  u16 *a1 = L + 8192,   *b1 = L + 12288;
  u16 *a2 = L + 16384,  *b2 = L + 20480;

  auto STAGE = [&](u16* la, u16* lb, int k0){
    __builtin_amdgcn_global_load_lds(&A[aoff + k0],                    la + sdo,        16, 0, 0);
    __builtin_amdgcn_global_load_lds(&A[aoff + (size_t)64*1024 + k0],  la + sdo + 2048, 16, 0, 0);
    __builtin_amdgcn_global_load_lds(&BT[boff + k0],                   lb + sdo,        16, 0, 0);
    __builtin_amdgcn_global_load_lds(&BT[boff + (size_t)64*1024 + k0], lb + sdo + 2048, 16, 0, 0);
  };

  f32x4 acc[4][4];
  #pragma unroll
  for (int m=0;m<4;m++)
    #pragma unroll
    for (int n=0;n<4;n++) acc[m][n] = (f32x4){0.f,0.f,0.f,0.f};

  STAGE(a0, b0, 0);
  STAGE(a1, b1, 32);
  for (int kt=0; kt<32; ++kt){
    if (kt < 31) asm volatile("s_waitcnt vmcnt(4)" ::: "memory");
    else         asm volatile("s_waitcnt vmcnt(0)" ::: "memory");
    __builtin_amdgcn_s_barrier();
    if (kt+2 < 32) STAGE(a2, b2, (kt+2)*32);
    short8 af[4], bfr[4];
    #pragma unroll
    for (int m=0;m<4;m++){
      int rrow = wr + m*16 + lr;
      af[m]  = *(const short8*)(a0 + rrow*32 + (((lg + (rrow>>1))&3)<<3));
    }
    #pragma unroll
    for (int n=0;n<4;n++){
      int rrow = wc + n*16 + lr;
      bfr[n] = *(const short8*)(b0 + rrow*32 + (((lg + (rrow>>1))&3)<<3));
    }
    __builtin_amdgcn_s_setprio(1);
    #pragma unroll
    for (int m=0;m<4;m++)
      #pragma unroll
      for (int n=0;n<4;n++)
        acc[m][n] = MFMA16(af[m], bfr[n], acc[m][n]);
    __builtin_amdgcn_s_setprio(0);
    { u16* tp=a0; a0=a1; a1=a2; a2=tp; }
    { u16* tp=b0; b0=b1; b1=b2; b2=tp; }
  }

  // ---- epilogue: fused RoPE on q/k (cols<2048), bf16 repack via LDS ----
  __syncthreads();                    // all waves done with K-loop LDS
  u16* Lb = L;                        // [128][132] u16 = 33.8 KB (fits 48 KB)
  const bool qk = (bn < 16);          // 128-col tiles: q 0..7, k 8..15
  const float qscale = (bn < 8) ? 0.125f : 1.0f;   // DK^-0.5 folded into q
  #pragma unroll
  for (int m=0;m<4;m++){
    if (qk){
      #pragma unroll
      for (int n=0;n<2;n++){
        float inv = exp2f((float)(n*16+lr) * (-13.287712379549449f/32.0f)); // 10000^(-i/32)
        #pragma unroll
        for (int r=0;r<4;r++){
          int lrow = wr + m*16 + lg*4 + r;
          int grow = bm*128 + lrow;
          float f = (float)(grow & 4095) * inv;
          float sn, cs; __sincosf(f, &sn, &cs);
          float x1 = acc[m][n][r], x2 = acc[m][n+2][r];
          Lb[lrow*132 + wc + n*16 + lr]     = f2bf((x1*cs - x2*sn)*qscale);
          Lb[lrow*132 + wc + (n+2)*16 + lr] = f2bf((x1*sn + x2*cs)*qscale);
        }
      }
    } else {
      #pragma unroll
      for (int n=0;n<4;n++)
        #pragma unroll
        for (int r=0;r<4;r++)
          Lb[(wr + m*16 + lg*4 + r)*132 + wc + n*16 + lr] = f2bf(acc[m][n][r]);
    }
  }
  __syncthreads();
  #pragma unroll
  for (int p=0;p<8;p++){
    int idx = p*256 + t;
    int row = idx>>4, gr = idx&15;
    *(short8*)&C[(size_t)(bm*128 + row)*6144 + bn*128 + gr*8] =
      *(const short8*)&Lb[row*132 + gr*8];
  }
}

// ---------------- NT GEMM (gemm2): counted-vmcnt 3-buffer pipeline + granule swizzle ----------------
__global__ __launch_bounds__(256) void gemm2_nt(const u16* __restrict__ A,
    const u16* __restrict__ BT, float* __restrict__ C, int M, int N, int K){
  __shared__ u16 L[3*8192];
  // XCD swizzle: 512 blocks = 8 XCDs x (8 bm x 8 bn); WoT (4MB) + 8 A-panels per XCD
  const int flat = blockIdx.y*gridDim.x + blockIdx.x;
  const int xcd  = flat & 7, loc = flat >> 3;    // loc in [0,64)
  const int bm   = xcd*8 + (loc & 7);            // [0,64)
  const int bn   = loc >> 3;                     // [0,8)
  const int t = threadIdx.x;
  const int w = t>>6, l = t&63;
  const int wr = (w>>1)*64, wc = (w&1)*64;
  const int lr = l&15, lg = l>>4;
  const int srow = t>>2;
  const int gsw  = ((t&3) - (t>>3)) & 3;
  const int scol = gsw*8;
  const size_t aoff = (size_t)(bm*128 + srow)*K + scol;
  const size_t boff = (size_t)(bn*128 + srow)*K + scol;
  const int sdo = t*8;

  u16 *a0 = L,          *b0 = L + 4096;
  u16 *a1 = L + 8192,   *b1 = L + 12288;
  u16 *a2 = L + 16384,  *b2 = L + 20480;

  auto STAGE = [&](u16* la, u16* lb, int k0){
    __builtin_amdgcn_global_load_lds(&A[aoff + k0],                 la + sdo,        16, 0, 0);
    __builtin_amdgcn_global_load_lds(&A[aoff + (size_t)64*K + k0],  la + sdo + 2048, 16, 0, 0);
    __builtin_amdgcn_global_load_lds(&BT[boff + k0],                lb + sdo,        16, 0, 0);
    __builtin_amdgcn_global_load_lds(&BT[boff + (size_t)64*K + k0], lb + sdo + 2048, 16, 0, 0);
  };

  f32x4 acc[4][4];
  for (int m=0;m<4;m++) for (int n=0;n<4;n++) acc[m][n] = (f32x4){0.f,0.f,0.f,0.f};

  const int NT = K >> 5;
  STAGE(a0, b0, 0);
  STAGE(a1, b1, 32);
  for (int kt=0; kt<NT; ++kt){
    if (kt < NT-1) asm volatile("s_waitcnt vmcnt(4)" ::: "memory");
    else           asm volatile("s_waitcnt vmcnt(0)" ::: "memory");
    __builtin_amdgcn_s_barrier();
    if (kt+2 < NT) STAGE(a2, b2, (kt+2)*32);
    short8 af[4], bfr[4];
    #pragma unroll
    for (int m=0;m<4;m++){
      int rrow = wr + m*16 + lr;
      af[m]  = *(const short8*)(a0 + rrow*32 + (((lg + (rrow>>1))&3)<<3));
    }
    #pragma unroll
    for (int n=0;n<4;n++){
      int rrow = wc + n*16 + lr;
      bfr[n] = *(const short8*)(b0 + rrow*32 + (((lg + (rrow>>1))&3)<<3));
    }
    __builtin_amdgcn_s_setprio(1);
    #pragma unroll
    for (int m=0;m<4;m++)
      #pragma unroll
      for (int n=0;n<4;n++)
        acc[m][n] = MFMA16(af[m], bfr[n], acc[m][n]);
    __builtin_amdgcn_s_setprio(0);
    { u16* tp=a0; a0=a1; a1=a2; a2=tp; }
    { u16* tp=b0; b0=b1; b1=b2; b2=tp; }
  }

  #pragma unroll
  for (int m=0;m<4;m++)
    #pragma unroll
    for (int n=0;n<4;n++){
    int row = bm*128 + wr + m*16 + lg*4;
    int col = bn*128 + wc + n*16 + lr;
    #pragma unroll
    for (int r=0;r<4;r++)
      C[(size_t)(row+r)*N + col] = acc[m][n][r];
  }
}

// ---------------- retention pass 1: XOR-granule-swizzled kT/vT, decay table ----------------
__global__ __launch_bounds__(256) void retention_r1(const u16* __restrict__ qkvg,
    u16* __restrict__ o, u16* __restrict__ states){
  int bid = blockIdx.x;                 // ((b*16+h)*64 + c)
  int c = bid & 63, h = (bid>>6)&15, b = bid>>10;
  int t = threadIdx.x, w = t>>6, l = t&63, lr = l&15, lg = l>>4;
  __shared__ u16 SH[17280];             // kT[64][64] | vT[128][64] | A_lds[64][72]; reused by epilogue
  __shared__ float pw[72];              // gamma^delta
  u16* kT    = SH;                      // granule-swizzled: g' = g ^ ((row>>3)&7)
  u16* vT    = SH + 4096;
  u16* A_lds = SH + 12288;              // [64][72] unswizzled
  float log2g = log2f(1.0f - exp2f(-5.0f - (float)h));
  if (t < 65) pw[t] = exp2f(log2g*(float)t);
  const size_t rowbase = (size_t)(b*4096 + c*64);
  __syncthreads();

  // stage + transpose k, v into LDS (paired u32 writes, XOR-granule swizzle)
  {
    int rp = t>>3, cg = t&7;            // k: 32 row-pairs x 8 col-groups
    int r0 = rp*2;
    short8 k0v = *(const short8*)&qkvg[(rowbase+r0  )*6144 + 1024 + h*64 + cg*8];
    short8 k1v = *(const short8*)&qkvg[(rowbase+r0+1)*6144 + 1024 + h*64 + cg*8];
    float d0 = pw[63-r0], d1 = pw[62-r0];
    #pragma unroll
    for (int j=0;j<8;j++){
      int d = cg*8+j;
      uint32_t pk = (uint32_t)f2bf(bf2f((u16)k0v[j])*d0) | ((uint32_t)f2bf(bf2f((u16)k1v[j])*d1)<<16);
      *(uint32_t*)&kT[d*64 + (((r0>>3) ^ (d>>3))<<3) + (r0&7)] = pk;
    }
    #pragma unroll
    for (int p=0;p<2;p++){              // v: 32 row-pairs x 16 col-groups
      int it = t + p*256;
      int vrp = it>>4, vcg = it&15;
      int vr0 = vrp*2;
      short8 v0 = *(const short8*)&qkvg[(rowbase+vr0  )*6144 + 2048 + h*128 + vcg*8];
      short8 v1 = *(const short8*)&qkvg[(rowbase+vr0+1)*6144 + 2048 + h*128 + vcg*8];
      #pragma unroll
      for (int j=0;j<8;j++){
        int e = vcg*8+j;
        uint32_t pv = (uint32_t)(u16)v0[j] | ((uint32_t)(u16)v1[j]<<16);
        *(uint32_t*)&vT[e*64 + (((vr0>>3) ^ ((e>>3)&7))<<3) + (vr0&7)] = pv;
      }
    }
  }

  // A = q @ k^T
  f32x4 z4 = {0.f,0.f,0.f,0.f};
  f32x4 accA[4] = {z4,z4,z4,z4};
  #pragma unroll
  for (int ks=0;ks<2;ks++){
    short8 aq = *(const short8*)&qkvg[(rowbase + w*16+lr)*6144 + h*64 + ks*32 + lg*8];
    #pragma unroll
    for (int n=0;n<4;n++){
      short8 bk = *(const short8*)&qkvg[(rowbase + n*16+lr)*6144 + 1024 + h*64 + ks*32 + lg*8];
      accA[n] = MFMA16(aq, bk, accA[n]);
    }
  }
  #pragma unroll
  for (int n=0;n<4;n++)
    #pragma unroll
    for (int r=0;r<4;r++){
    int i = w*16 + lg*4 + r, j = n*16 + lr;
    float v = (i>=j) ? accA[n][r]*pw[i-j] : 0.0f;
    A_lds[i*72 + j] = f2bf(v);
  }
  __syncthreads();

  // o_intra = A @ v ; S_c = kdT @ v   (swizzled granule reads: broadcast, conflict-free)
  f32x4 accO[8], accS[8];
  #pragma unroll
  for (int n=0;n<8;n++){ accO[n]=z4; accS[n]=z4; }
  #pragma unroll
  for (int ks=0;ks<2;ks++){
    int rk = w*16+lr;
    short8 aA = *(const short8*)&A_lds[rk*72 + ks*32+lg*8];
    short8 aK = *(const short8*)&kT[rk*64 + (((ks*4+lg) ^ (rk>>3))<<3)];
    #pragma unroll
    for (int n=0;n<8;n++){
      int e2 = n*16+lr;
      short8 bv = *(const short8*)&vT[e2*64 + (((ks*4+lg) ^ ((e2>>3)&7))<<3)];
      accO[n] = MFMA16(aA, bv, accO[n]);
      accS[n] = MFMA16(aK, bv, accS[n]);
    }
  }

  // -------- coalesced epilogue: repack via LDS --------
  __syncthreads();
  u16* oB = SH;                          // [64][132]
  u16* sB = SH + 8448;                   // [128][68]
  #pragma unroll
  for (int n=0;n<8;n++)
    #pragma unroll
    for (int r=0;r<4;r++){
    int i = w*16 + lg*4 + r, e = n*16 + lr;
    oB[i*132 + e] = f2bf(accO[n][r]);
    sB[e*68 + i]  = f2bf(accS[n][r]);
  }
  __syncthreads();
  const size_t ob = rowbase*2048 + h*128;
  const size_t sb = ((size_t)(b*16+h)*64 + c)*8192;   // states[b][h][c][e=128][d=64]
  {
    int orow = t>>2, ocol = (t&3)*32;
    #pragma unroll
    for (int q=0;q<4;q++)
      *(short8*)&o[ob + (size_t)orow*2048 + ocol + q*8] = *(const short8*)&oB[orow*132 + ocol + q*8];
    int se = t>>1, sd = (t&1)*32;
    #pragma unroll
    for (int q=0;q<4;q++)
      *(short8*)&states[sb + (size_t)se*64 + sd + q*8] = *(const short8*)&sB[se*68 + sd + q*8];
  }
}

// ---------------- retention pass 2: scan over chunks, o += (q*dq) @ S ----------------
__global__ __launch_bounds__(256) void retention_r2(const u16* __restrict__ qkvg,
    const u16* __restrict__ states, u16* __restrict__ o){
  int bid = blockIdx.x;
  int vblk = bid & 7, h = (bid>>3)&15, b = bid>>7;
  int t = threadIdx.x, w = t>>6, l = t&63, lr = l&15, lg = l>>4;
  int e0 = vblk*16;
  float log2g = log2f(1.0f - exp2f(-5.0f - (float)h));
  float gC = exp2f(64.0f*log2g);
  float dqv[4];
  #pragma unroll
  for (int r=0;r<4;r++) dqv[r] = exp2f(log2g*(float)(w*16 + lg*4 + r + 1));
  float st[16];
  #pragma unroll
  for (int i=0;i<16;i++) st[i]=0.f;
  const size_t sbase = ((size_t)(b*16+h)*64)*8192 + (size_t)(e0+lr)*64 + lg*8;
  const size_t qb = (size_t)(b*4096)*6144 + h*64 + (size_t)(w*16+lr)*6144 + lg*8;
  const size_t obh = (size_t)(b*4096)*2048 + h*128 + e0 + lr;
  short8 nsc0 = *(const short8*)&states[sbase];
  short8 nsc1 = *(const short8*)&states[sbase + 32];
  short8 naq0 = *(const short8*)&qkvg[qb];
  short8 naq1 = *(const short8*)&qkvg[qb + 32];
  for (int c=0;c<64;c++){
    short8 sc0 = nsc0, sc1 = nsc1, aq0 = naq0, aq1 = naq1;
    if (c < 63){
      nsc0 = *(const short8*)&states[sbase + (size_t)(c+1)*8192];
      nsc1 = *(const short8*)&states[sbase + (size_t)(c+1)*8192 + 32];
      naq0 = *(const short8*)&qkvg[qb + (size_t)(c+1)*64*6144];
      naq1 = *(const short8*)&qkvg[qb + (size_t)(c+1)*64*6144 + 32];
    }
    f32x4 acc = {0.f,0.f,0.f,0.f};
    short8 bs0, bs1;
    #pragma unroll
    for (int dd=0;dd<8;dd++) bs0[dd] = (short)f2bf(st[dd]);
    #pragma unroll
    for (int dd=0;dd<8;dd++) bs1[dd] = (short)f2bf(st[dd+8]);
    acc = MFMA16(aq0, bs0, acc);
    acc = MFMA16(aq1, bs1, acc);
    #pragma unroll
    for (int r=0;r<4;r++){
      int i = w*16 + lg*4 + r;
      size_t oi = obh + (size_t)(c*64 + i)*2048;
      o[oi] = f2bf(bf2f(o[oi]) + dqv[r]*acc[r]);
    }
    #pragma unroll
    for (int i2=0;i2<8;i2++) st[i2]   = gC*st[i2]   + bf2f((u16)sc0[i2]);
    #pragma unroll
    for (int i2=0;i2<8;i2++) st[i2+8] = gC*st[i2+8] + bf2f((u16)sc1[i2]);
  }
}

// ---------------- fused RMSNorm (over DV=128) + swish gate -> bf16 ----------------
__global__ __launch_bounds__(256) void norm_gate(const u16* __restrict__ o,
    const u16* __restrict__ qkvg, const float* __restrict__ gnw, u16* __restrict__ og){
  int rowh = blockIdx.x*4 + (threadIdx.x>>6);
  int l = threadIdx.x & 63;
  int row = rowh >> 4, h = rowh & 15;
  uint32_t vv = *(const uint32_t*)(o + (size_t)row*2048 + h*128 + l*2);
  float v0 = bf2f((u16)(vv&0xFFFF)), v1 = bf2f((u16)(vv>>16));
  float ss = v0*v0 + v1*v1;
  #pragma unroll
  for (int off=32; off; off>>=1) ss += __shfl_xor(ss, off);
  float rs = rsqrtf(ss*(1.0f/128.0f) + 1e-5f);
  uint32_t gg = *(const uint32_t*)(qkvg + (size_t)row*6144 + 4096 + h*128 + l*2);
  float g0 = bf2f((u16)(gg&0xFFFF)), g1 = bf2f((u16)(gg>>16));
  float r0 = v0*rs*gnw[l*2]   * (g0/(1.f+expf(-g0)));
  float r1 = v1*rs*gnw[l*2+1] * (g1/(1.f+expf(-g1)));
  uint32_t pack = (uint32_t)f2bf(r0) | ((uint32_t)f2bf(r1)<<16);
  *(uint32_t*)(og + (size_t)row*2048 + h*128 + l*2) = pack;
}

extern "C" void kernel_launch(void* const* d_in, const int* in_sizes, int n_in,
                              void* d_out, int out_size, void* d_ws, size_t ws_size,
                              hipStream_t stream){
  const float* x   = (const float*)d_in[0];
  const float* Wq  = (const float*)d_in[1];
  const float* Wk  = (const float*)d_in[2];
  const float* Wv  = (const float*)d_in[3];
  const float* Wg  = (const float*)d_in[4];
  const float* Wo  = (const float*)d_in[5];
  const float* gnw = (const float*)d_in[6];
  float* out = (float*)d_out;

  const size_t NEED = 171966464ull;    // 164 MB
  if (ws_size < NEED) return;

  char* base = (char*)d_ws;
  u16* qkvg  = (u16*)(base);                 // [8192][6144] bf16            [0,96M)
  u16* obuf  = (u16*)(base + 100663296);     // [8192][2048] bf16            [96M,128M)
  u16* WoT   = (u16*)(base + 134217728);     // [1024][2048] bf16            [128M,132M)
  u16* xb    = (u16*)(base + 138412032);     // [8192][1024] bf16            dead after gemm1
  u16* WcatT = (u16*)(base + 155189248);     // [6144][1024] bf16            dead after gemm1
  u16* stt   = (u16*)(base + 138412032);     // [B][H][64][128][64] bf16     alias, live r1->r2
  u16* og    = (u16*)(base + 138412032);     // [8192][2048] bf16            alias, live ng->gemm2

  prep<<<16384,256,0,stream>>>(x, xb, Wq, Wk, Wv, Wg, Wo, WcatT, WoT);
  gemm1_128<<<dim3(48,64),256,0,stream>>>(xb, WcatT, qkvg);
  retention_r1<<<2048,256,0,stream>>>(qkvg, obuf, stt);
  retention_r2<<<256,256,0,stream>>>(qkvg, stt, obuf);
  norm_gate<<<32768,256,0,stream>>>(obuf, qkvg, gnw, og);
  gemm2_nt<<<dim3(8,64),256,0,stream>>>(og, WoT, out, 8192, 1024, 2048);
}

// Round 6
// 323.293 us; speedup vs baseline: 1.0031x; 1.0031x over previous
//
#include <hip/hip_runtime.h>
#include <stdint.h>
#include <type_traits>

typedef unsigned short u16;
typedef __attribute__((ext_vector_type(8))) short short8;
typedef __attribute__((ext_vector_type(4))) float f32x4;

#define MFMA16(a,b,c) __builtin_amdgcn_mfma_f32_16x16x32_bf16(a,b,c,0,0,0)

__device__ __forceinline__ u16 f2bf(float f){
  uint32_t u = __builtin_bit_cast(uint32_t, f);
  u += 0x7FFFu + ((u>>16)&1u);
  return (u16)(u>>16);
}
__device__ __forceinline__ float bf2f(u16 h){
  uint32_t u = ((uint32_t)h)<<16;
  return __builtin_bit_cast(float, u);
}

// ---------------- prep: cast x f32->bf16 (bid<8192) + all weight transposes ----------------
__global__ __launch_bounds__(256) void prep(const float* __restrict__ x, u16* __restrict__ xb,
    const float* __restrict__ Wq, const float* __restrict__ Wk, const float* __restrict__ Wv,
    const float* __restrict__ Wg, const float* __restrict__ Wo,
    u16* __restrict__ WcatT, u16* __restrict__ WoT){
  int bid = blockIdx.x;
  if (bid < 8192){
    int i = (bid*256 + threadIdx.x)*4;
    float4 v = *(const float4*)&x[i];
    uint2 u;
    u.x = (uint32_t)f2bf(v.x) | ((uint32_t)f2bf(v.y)<<16);
    u.y = (uint32_t)f2bf(v.z) | ((uint32_t)f2bf(v.w)<<16);
    *(uint2*)&xb[i] = u;
    return;
  }
  bid -= 8192;
  const float* src; u16* dst; int R, Cc, tc, tr;
  if (bid < 1024){        src=Wq; dst=WcatT;             R=1024; Cc=1024; int b=bid;      tc=(b&31)*32; tr=(b>>5)*32; }
  else if (bid < 2048){   src=Wk; dst=WcatT+1024*1024;   R=1024; Cc=1024; int b=bid-1024; tc=(b&31)*32; tr=(b>>5)*32; }
  else if (bid < 4096){   src=Wv; dst=WcatT+2048*1024;   R=1024; Cc=2048; int b=bid-2048; tc=(b&63)*32; tr=(b>>6)*32; }
  else if (bid < 6144){   src=Wg; dst=WcatT+4096*1024;   R=1024; Cc=2048; int b=bid-4096; tc=(b&63)*32; tr=(b>>6)*32; }
  else {                  src=Wo; dst=WoT;               R=2048; Cc=1024; int b=bid-6144; tc=(b&31)*32; tr=(b>>5)*32; }
  __shared__ float tile[32][33];
  int lr = threadIdx.x>>5, lc = threadIdx.x&31;
  #pragma unroll
  for (int p=0;p<4;p++)
    tile[lr+p*8][lc] = src[(size_t)(tr+lr+p*8)*Cc + tc + lc];
  __syncthreads();
  #pragma unroll
  for (int p=0;p<4;p++)
    dst[(size_t)(tc+lr+p*8)*R + tr + lc] = f2bf(tile[lc][lr+p*8]);
}

// =================================================================
// gemm1: Round 6 — IDENTICAL resubmit of round-5's gemm1_128 (A/B re-run).
// Round 5: gemm1 167->146us (counter-verified) but total 298->324 via +47us
// in the five UNCHANGED kernels — no code-level causal channel. This round
// disambiguates environmental noise vs real carry-over (DVFS) before
// deciding keep-vs-revert. 128x128 tile, m97-class K-loop, 3-buffer
// counted-vmcnt, XCD swizzle, fused RoPE bf16 epilogue.
// =================================================================
__global__ __launch_bounds__(256) void gemm1_128(const u16* __restrict__ A,
    const u16* __restrict__ BT, u16* __restrict__ C){
  __shared__ u16 L[3*8192];           // 3 x (A 8KB | B 8KB) = 48 KiB
  // XCD swizzle: 3072 blocks = 8 XCDs x (8 bm x 48 bn). Per XCD: 8 A-panels
  // (2 MB) L2-resident all kernel; B-panel reused 8x per bn sweep.
  const int flat = blockIdx.y*48 + blockIdx.x;   // grid (48,64)
  const int xcd  = flat & 7, loc = flat >> 3;    // loc in [0,384)
  const int bm   = xcd*8 + (loc & 7);            // [0,64)
  const int bn   = loc >> 3;                     // [0,48)
  const int t = threadIdx.x;
  const int w = t>>6, l = t&63;
  const int wr = (w>>1)*64, wc = (w&1)*64;
  const int lr = l&15, lg = l>>4;
  const int srow = t>>2;
  const int gsw  = ((t&3) - (t>>3)) & 3;
  const int scol = gsw*8;
  const size_t aoff = (size_t)(bm*128 + srow)*1024 + scol;
  const size_t boff = (size_t)(bn*128 + srow)*1024 + scol;
  const int sdo = t*8;

  u16 *a0 = L,          *b0 = L + 4096;
  u16 *a1 = L + 8192,   *b1 = L + 12288;
  u16 *a2 = L + 16384,  *b2 = L + 20480;

  auto STAGE = [&](u16* la, u16* lb, int k0){
    __builtin_amdgcn_global_load_lds(&A[aoff + k0],                    la + sdo,        16, 0, 0);
    __builtin_amdgcn_global_load_lds(&A[aoff + (size_t)64*1024 + k0],  la + sdo + 2048, 16, 0, 0);
    __builtin_amdgcn_global_load_lds(&BT[boff + k0],                   lb + sdo,        16, 0, 0);
    __builtin_amdgcn_global_load_lds(&BT[boff + (size_t)64*1024 + k0], lb + sdo + 2048, 16, 0, 0);
  };

  f32x4 acc[4][4];
  #pragma unroll
  for (int m=0;m<4;m++)
    #pragma unroll
    for (int n=0;n<4;n++) acc[m][n] = (f32x4){0.f,0.f,0.f,0.f};

  STAGE(a0, b0, 0);
  STAGE(a1, b1, 32);
  for (int kt=0; kt<32; ++kt){
    if (kt < 31) asm volatile("s_waitcnt vmcnt(4)" ::: "memory");
    else         asm volatile("s_waitcnt vmcnt(0)" ::: "memory");
    __builtin_amdgcn_s_barrier();
    if (kt+2 < 32) STAGE(a2, b2, (kt+2)*32);
    short8 af[4], bfr[4];
    #pragma unroll
    for (int m=0;m<4;m++){
      int rrow = wr + m*16 + lr;
      af[m]  = *(const short8*)(a0 + rrow*32 + (((lg + (rrow>>1))&3)<<3));
    }
    #pragma unroll
    for (int n=0;n<4;n++){
      int rrow = wc + n*16 + lr;
      bfr[n] = *(const short8*)(b0 + rrow*32 + (((lg + (rrow>>1))&3)<<3));
    }
    __builtin_amdgcn_s_setprio(1);
    #pragma unroll
    for (int m=0;m<4;m++)
      #pragma unroll
      for (int n=0;n<4;n++)
        acc[m][n] = MFMA16(af[m], bfr[n], acc[m][n]);
    __builtin_amdgcn_s_setprio(0);
    { u16* tp=a0; a0=a1; a1=a2; a2=tp; }
    { u16* tp=b0; b0=b1; b1=b2; b2=tp; }
  }

  // ---- epilogue: fused RoPE on q/k (cols<2048), bf16 repack via LDS ----
  __syncthreads();                    // all waves done with K-loop LDS
  u16* Lb = L;                        // [128][132] u16 = 33.8 KB (fits 48 KB)
  const bool qk = (bn < 16);          // 128-col tiles: q 0..7, k 8..15
  const float qscale = (bn < 8) ? 0.125f : 1.0f;   // DK^-0.5 folded into q
  #pragma unroll
  for (int m=0;m<4;m++){
    if (qk){
      #pragma unroll
      for (int n=0;n<2;n++){
        float inv = exp2f((float)(n*16+lr) * (-13.287712379549449f/32.0f)); // 10000^(-i/32)
        #pragma unroll
        for (int r=0;r<4;r++){
          int lrow = wr + m*16 + lg*4 + r;
          int grow = bm*128 + lrow;
          float f = (float)(grow & 4095) * inv;
          float sn, cs; __sincosf(f, &sn, &cs);
          float x1 = acc[m][n][r], x2 = acc[m][n+2][r];
          Lb[lrow*132 + wc + n*16 + lr]     = f2bf((x1*cs - x2*sn)*qscale);
          Lb[lrow*132 + wc + (n+2)*16 + lr] = f2bf((x1*sn + x2*cs)*qscale);
        }
      }
    } else {
      #pragma unroll
      for (int n=0;n<4;n++)
        #pragma unroll
        for (int r=0;r<4;r++)
          Lb[(wr + m*16 + lg*4 + r)*132 + wc + n*16 + lr] = f2bf(acc[m][n][r]);
    }
  }
  __syncthreads();
  #pragma unroll
  for (int p=0;p<8;p++){
    int idx = p*256 + t;
    int row = idx>>4, gr = idx&15;
    *(short8*)&C[(size_t)(bm*128 + row)*6144 + bn*128 + gr*8] =
      *(const short8*)&Lb[row*132 + gr*8];
  }
}

// ---------------- NT GEMM (gemm2): counted-vmcnt 3-buffer pipeline + granule swizzle ----------------
__global__ __launch_bounds__(256) void gemm2_nt(const u16* __restrict__ A,
    const u16* __restrict__ BT, float* __restrict__ C, int M, int N, int K){
  __shared__ u16 L[3*8192];
  // XCD swizzle: 512 blocks = 8 XCDs x (8 bm x 8 bn); WoT (4MB) + 8 A-panels per XCD
  const int flat = blockIdx.y*gridDim.x + blockIdx.x;
  const int xcd  = flat & 7, loc = flat >> 3;    // loc in [0,64)
  const int bm   = xcd*8 + (loc & 7);            // [0,64)
  const int bn   = loc >> 3;                     // [0,8)
  const int t = threadIdx.x;
  const int w = t>>6, l = t&63;
  const int wr = (w>>1)*64, wc = (w&1)*64;
  const int lr = l&15, lg = l>>4;
  const int srow = t>>2;
  const int gsw  = ((t&3) - (t>>3)) & 3;
  const int scol = gsw*8;
  const size_t aoff = (size_t)(bm*128 + srow)*K + scol;
  const size_t boff = (size_t)(bn*128 + srow)*K + scol;
  const int sdo = t*8;

  u16 *a0 = L,          *b0 = L + 4096;
  u16 *a1 = L + 8192,   *b1 = L + 12288;
  u16 *a2 = L + 16384,  *b2 = L + 20480;

  auto STAGE = [&](u16* la, u16* lb, int k0){
    __builtin_amdgcn_global_load_lds(&A[aoff + k0],                 la + sdo,        16, 0, 0);
    __builtin_amdgcn_global_load_lds(&A[aoff + (size_t)64*K + k0],  la + sdo + 2048, 16, 0, 0);
    __builtin_amdgcn_global_load_lds(&BT[boff + k0],                lb + sdo,        16, 0, 0);
    __builtin_amdgcn_global_load_lds(&BT[boff + (size_t)64*K + k0], lb + sdo + 2048, 16, 0, 0);
  };

  f32x4 acc[4][4];
  for (int m=0;m<4;m++) for (int n=0;n<4;n++) acc[m][n] = (f32x4){0.f,0.f,0.f,0.f};

  const int NT = K >> 5;
  STAGE(a0, b0, 0);
  STAGE(a1, b1, 32);
  for (int kt=0; kt<NT; ++kt){
    if (kt < NT-1) asm volatile("s_waitcnt vmcnt(4)" ::: "memory");
    else           asm volatile("s_waitcnt vmcnt(0)" ::: "memory");
    __builtin_amdgcn_s_barrier();
    if (kt+2 < NT) STAGE(a2, b2, (kt+2)*32);
    short8 af[4], bfr[4];
    #pragma unroll
    for (int m=0;m<4;m++){
      int rrow = wr + m*16 + lr;
      af[m]  = *(const short8*)(a0 + rrow*32 + (((lg + (rrow>>1))&3)<<3));
    }
    #pragma unroll
    for (int n=0;n<4;n++){
      int rrow = wc + n*16 + lr;
      bfr[n] = *(const short8*)(b0 + rrow*32 + (((lg + (rrow>>1))&3)<<3));
    }
    __builtin_amdgcn_s_setprio(1);
    #pragma unroll
    for (int m=0;m<4;m++)
      #pragma unroll
      for (int n=0;n<4;n++)
        acc[m][n] = MFMA16(af[m], bfr[n], acc[m][n]);
    __builtin_amdgcn_s_setprio(0);
    { u16* tp=a0; a0=a1; a1=a2; a2=tp; }
    { u16* tp=b0; b0=b1; b1=b2; b2=tp; }
  }

  #pragma unroll
  for (int m=0;m<4;m++)
    #pragma unroll
    for (int n=0;n<4;n++){
    int row = bm*128 + wr + m*16 + lg*4;
    int col = bn*128 + wc + n*16 + lr;
    #pragma unroll
    for (int r=0;r<4;r++)
      C[(size_t)(row+r)*N + col] = acc[m][n][r];
  }
}

// ---------------- retention pass 1: XOR-granule-swizzled kT/vT, decay table ----------------
__global__ __launch_bounds__(256) void retention_r1(const u16* __restrict__ qkvg,
    u16* __restrict__ o, u16* __restrict__ states){
  int bid = blockIdx.x;                 // ((b*16+h)*64 + c)
  int c = bid & 63, h = (bid>>6)&15, b = bid>>10;
  int t = threadIdx.x, w = t>>6, l = t&63, lr = l&15, lg = l>>4;
  __shared__ u16 SH[17280];             // kT[64][64] | vT[128][64] | A_lds[64][72]; reused by epilogue
  __shared__ float pw[72];              // gamma^delta
  u16* kT    = SH;                      // granule-swizzled: g' = g ^ ((row>>3)&7)
  u16* vT    = SH + 4096;
  u16* A_lds = SH + 12288;              // [64][72] unswizzled
  float log2g = log2f(1.0f - exp2f(-5.0f - (float)h));
  if (t < 65) pw[t] = exp2f(log2g*(float)t);
  const size_t rowbase = (size_t)(b*4096 + c*64);
  __syncthreads();

  // stage + transpose k, v into LDS (paired u32 writes, XOR-granule swizzle)
  {
    int rp = t>>3, cg = t&7;            // k: 32 row-pairs x 8 col-groups
    int r0 = rp*2;
    short8 k0v = *(const short8*)&qkvg[(rowbase+r0  )*6144 + 1024 + h*64 + cg*8];
    short8 k1v = *(const short8*)&qkvg[(rowbase+r0+1)*6144 + 1024 + h*64 + cg*8];
    float d0 = pw[63-r0], d1 = pw[62-r0];
    #pragma unroll
    for (int j=0;j<8;j++){
      int d = cg*8+j;
      uint32_t pk = (uint32_t)f2bf(bf2f((u16)k0v[j])*d0) | ((uint32_t)f2bf(bf2f((u16)k1v[j])*d1)<<16);
      *(uint32_t*)&kT[d*64 + (((r0>>3) ^ (d>>3))<<3) + (r0&7)] = pk;
    }
    #pragma unroll
    for (int p=0;p<2;p++){              // v: 32 row-pairs x 16 col-groups
      int it = t + p*256;
      int vrp = it>>4, vcg = it&15;
      int vr0 = vrp*2;
      short8 v0 = *(const short8*)&qkvg[(rowbase+vr0  )*6144 + 2048 + h*128 + vcg*8];
      short8 v1 = *(const short8*)&qkvg[(rowbase+vr0+1)*6144 + 2048 + h*128 + vcg*8];
      #pragma unroll
      for (int j=0;j<8;j++){
        int e = vcg*8+j;
        uint32_t pv = (uint32_t)(u16)v0[j] | ((uint32_t)(u16)v1[j]<<16);
        *(uint32_t*)&vT[e*64 + (((vr0>>3) ^ ((e>>3)&7))<<3) + (vr0&7)] = pv;
      }
    }
  }

  // A = q @ k^T
  f32x4 z4 = {0.f,0.f,0.f,0.f};
  f32x4 accA[4] = {z4,z4,z4,z4};
  #pragma unroll
  for (int ks=0;ks<2;ks++){
    short8 aq = *(const short8*)&qkvg[(rowbase + w*16+lr)*6144 + h*64 + ks*32 + lg*8];
    #pragma unroll
    for (int n=0;n<4;n++){
      short8 bk = *(const short8*)&qkvg[(rowbase + n*16+lr)*6144 + 1024 + h*64 + ks*32 + lg*8];
      accA[n] = MFMA16(aq, bk, accA[n]);
    }
  }
  #pragma unroll
  for (int n=0;n<4;n++)
    #pragma unroll
    for (int r=0;r<4;r++){
    int i = w*16 + lg*4 + r, j = n*16 + lr;
    float v = (i>=j) ? accA[n][r]*pw[i-j] : 0.0f;
    A_lds[i*72 + j] = f2bf(v);
  }
  __syncthreads();

  // o_intra = A @ v ; S_c = kdT @ v   (swizzled granule reads: broadcast, conflict-free)
  f32x4 accO[8], accS[8];
  #pragma unroll
  for (int n=0;n<8;n++){ accO[n]=z4; accS[n]=z4; }
  #pragma unroll
  for (int ks=0;ks<2;ks++){
    int rk = w*16+lr;
    short8 aA = *(const short8*)&A_lds[rk*72 + ks*32+lg*8];
    short8 aK = *(const short8*)&kT[rk*64 + (((ks*4+lg) ^ (rk>>3))<<3)];
    #pragma unroll
    for (int n=0;n<8;n++){
      int e2 = n*16+lr;
      short8 bv = *(const short8*)&vT[e2*64 + (((ks*4+lg) ^ ((e2>>3)&7))<<3)];
      accO[n] = MFMA16(aA, bv, accO[n]);
      accS[n] = MFMA16(aK, bv, accS[n]);
    }
  }

  // -------- coalesced epilogue: repack via LDS --------
  __syncthreads();
  u16* oB = SH;                          // [64][132]
  u16* sB = SH + 8448;                   // [128][68]
  #pragma unroll
  for (int n=0;n<8;n++)
    #pragma unroll
    for (int r=0;r<4;r++){
    int i = w*16 + lg*4 + r, e = n*16 + lr;
    oB[i*132 + e] = f2bf(accO[n][r]);
    sB[e*68 + i]  = f2bf(accS[n][r]);
  }
  __syncthreads();
  const size_t ob = rowbase*2048 + h*128;
  const size_t sb = ((size_t)(b*16+h)*64 + c)*8192;   // states[b][h][c][e=128][d=64]
  {
    int orow = t>>2, ocol = (t&3)*32;
    #pragma unroll
    for (int q=0;q<4;q++)
      *(short8*)&o[ob + (size_t)orow*2048 + ocol + q*8] = *(const short8*)&oB[orow*132 + ocol + q*8];
    int se = t>>1, sd = (t&1)*32;
    #pragma unroll
    for (int q=0;q<4;q++)
      *(short8*)&states[sb + (size_t)se*64 + sd + q*8] = *(const short8*)&sB[se*68 + sd + q*8];
  }
}

// ---------------- retention pass 2: scan over chunks, o += (q*dq) @ S ----------------
__global__ __launch_bounds__(256) void retention_r2(const u16* __restrict__ qkvg,
    const u16* __restrict__ states, u16* __restrict__ o){
  int bid = blockIdx.x;
  int vblk = bid & 7, h = (bid>>3)&15, b = bid>>7;
  int t = threadIdx.x, w = t>>6, l = t&63, lr = l&15, lg = l>>4;
  int e0 = vblk*16;
  float log2g = log2f(1.0f - exp2f(-5.0f - (float)h));
  float gC = exp2f(64.0f*log2g);
  float dqv[4];
  #pragma unroll
  for (int r=0;r<4;r++) dqv[r] = exp2f(log2g*(float)(w*16 + lg*4 + r + 1));
  float st[16];
  #pragma unroll
  for (int i=0;i<16;i++) st[i]=0.f;
  const size_t sbase = ((size_t)(b*16+h)*64)*8192 + (size_t)(e0+lr)*64 + lg*8;
  const size_t qb = (size_t)(b*4096)*6144 + h*64 + (size_t)(w*16+lr)*6144 + lg*8;
  const size_t obh = (size_t)(b*4096)*2048 + h*128 + e0 + lr;
  short8 nsc0 = *(const short8*)&states[sbase];
  short8 nsc1 = *(const short8*)&states[sbase + 32];
  short8 naq0 = *(const short8*)&qkvg[qb];
  short8 naq1 = *(const short8*)&qkvg[qb + 32];
  for (int c=0;c<64;c++){
    short8 sc0 = nsc0, sc1 = nsc1, aq0 = naq0, aq1 = naq1;
    if (c < 63){
      nsc0 = *(const short8*)&states[sbase + (size_t)(c+1)*8192];
      nsc1 = *(const short8*)&states[sbase + (size_t)(c+1)*8192 + 32];
      naq0 = *(const short8*)&qkvg[qb + (size_t)(c+1)*64*6144];
      naq1 = *(const short8*)&qkvg[qb + (size_t)(c+1)*64*6144 + 32];
    }
    f32x4 acc = {0.f,0.f,0.f,0.f};
    short8 bs0, bs1;
    #pragma unroll
    for (int dd=0;dd<8;dd++) bs0[dd] = (short)f2bf(st[dd]);
    #pragma unroll
    for (int dd=0;dd<8;dd++) bs1[dd] = (short)f2bf(st[dd+8]);
    acc = MFMA16(aq0, bs0, acc);
    acc = MFMA16(aq1, bs1, acc);
    #pragma unroll
    for (int r=0;r<4;r++){
      int i = w*16 + lg*4 + r;
      size_t oi = obh + (size_t)(c*64 + i)*2048;
      o[oi] = f2bf(bf2f(o[oi]) + dqv[r]*acc[r]);
    }
    #pragma unroll
    for (int i2=0;i2<8;i2++) st[i2]   = gC*st[i2]   + bf2f((u16)sc0[i2]);
    #pragma unroll
    for (int i2=0;i2<8;i2++) st[i2+8] = gC*st[i2+8] + bf2f((u16)sc1[i2]);
  }
}

// ---------------- fused RMSNorm (over DV=128) + swish gate -> bf16 ----------------
__global__ __launch_bounds__(256) void norm_gate(const u16* __restrict__ o,
    const u16* __restrict__ qkvg, const float* __restrict__ gnw, u16* __restrict__ og){
  int rowh = blockIdx.x*4 + (threadIdx.x>>6);
  int l = threadIdx.x & 63;
  int row = rowh >> 4, h = rowh & 15;
  uint32_t vv = *(const uint32_t*)(o + (size_t)row*2048 + h*128 + l*2);
  float v0 = bf2f((u16)(vv&0xFFFF)), v1 = bf2f((u16)(vv>>16));
  float ss = v0*v0 + v1*v1;
  #pragma unroll
  for (int off=32; off; off>>=1) ss += __shfl_xor(ss, off);
  float rs = rsqrtf(ss*(1.0f/128.0f) + 1e-5f);
  uint32_t gg = *(const uint32_t*)(qkvg + (size_t)row*6144 + 4096 + h*128 + l*2);
  float g0 = bf2f((u16)(gg&0xFFFF)), g1 = bf2f((u16)(gg>>16));
  float r0 = v0*rs*gnw[l*2]   * (g0/(1.f+expf(-g0)));
  float r1 = v1*rs*gnw[l*2+1] * (g1/(1.f+expf(-g1)));
  uint32_t pack = (uint32_t)f2bf(r0) | ((uint32_t)f2bf(r1)<<16);
  *(uint32_t*)(og + (size_t)row*2048 + h*128 + l*2) = pack;
}

extern "C" void kernel_launch(void* const* d_in, const int* in_sizes, int n_in,
                              void* d_out, int out_size, void* d_ws, size_t ws_size,
                              hipStream_t stream){
  const float* x   = (const float*)d_in[0];
  const float* Wq  = (const float*)d_in[1];
  const float* Wk  = (const float*)d_in[2];
  const float* Wv  = (const float*)d_in[3];
  const float* Wg  = (const float*)d_in[4];
  const float* Wo  = (const float*)d_in[5];
  const float* gnw = (const float*)d_in[6];
  float* out = (float*)d_out;

  const size_t NEED = 171966464ull;    // 164 MB
  if (ws_size < NEED) return;

  char* base = (char*)d_ws;
  u16* qkvg  = (u16*)(base);                 // [8192][6144] bf16            [0,96M)
  u16* obuf  = (u16*)(base + 100663296);     // [8192][2048] bf16            [96M,128M)
  u16* WoT   = (u16*)(base + 134217728);     // [1024][2048] bf16            [128M,132M)
  u16* xb    = (u16*)(base + 138412032);     // [8192][1024] bf16            dead after gemm1
  u16* WcatT = (u16*)(base + 155189248);     // [6144][1024] bf16            dead after gemm1
  u16* stt   = (u16*)(base + 138412032);     // [B][H][64][128][64] bf16     alias, live r1->r2
  u16* og    = (u16*)(base + 138412032);     // [8192][2048] bf16            alias, live ng->gemm2

  prep<<<16384,256,0,stream>>>(x, xb, Wq, Wk, Wv, Wg, Wo, WcatT, WoT);
  gemm1_128<<<dim3(48,64),256,0,stream>>>(xb, WcatT, qkvg);
  retention_r1<<<2048,256,0,stream>>>(qkvg, obuf, stt);
  retention_r2<<<256,256,0,stream>>>(qkvg, stt, obuf);
  norm_gate<<<32768,256,0,stream>>>(obuf, qkvg, gnw, og);
  gemm2_nt<<<dim3(8,64),256,0,stream>>>(og, WoT, out, 8192, 1024, 2048);
}

// Round 7
// 292.922 us; speedup vs baseline: 1.1071x; 1.1037x over previous
//
#include <hip/hip_runtime.h>
#include <stdint.h>
#include <type_traits>

typedef unsigned short u16;
typedef __attribute__((ext_vector_type(8))) short short8;
typedef __attribute__((ext_vector_type(4))) float f32x4;

#define MFMA16(a,b,c) __builtin_amdgcn_mfma_f32_16x16x32_bf16(a,b,c,0,0,0)

__device__ __forceinline__ u16 f2bf(float f){
  uint32_t u = __builtin_bit_cast(uint32_t, f);
  u += 0x7FFFu + ((u>>16)&1u);
  return (u16)(u>>16);
}
__device__ __forceinline__ float bf2f(u16 h){
  uint32_t u = ((uint32_t)h)<<16;
  return __builtin_bit_cast(float, u);
}

// ---------------- prep: cast x f32->bf16 (bid<8192) + all weight transposes ----------------
__global__ __launch_bounds__(256) void prep(const float* __restrict__ x, u16* __restrict__ xb,
    const float* __restrict__ Wq, const float* __restrict__ Wk, const float* __restrict__ Wv,
    const float* __restrict__ Wg, const float* __restrict__ Wo,
    u16* __restrict__ WcatT, u16* __restrict__ WoT){
  int bid = blockIdx.x;
  if (bid < 8192){
    int i = (bid*256 + threadIdx.x)*4;
    float4 v = *(const float4*)&x[i];
    uint2 u;
    u.x = (uint32_t)f2bf(v.x) | ((uint32_t)f2bf(v.y)<<16);
    u.y = (uint32_t)f2bf(v.z) | ((uint32_t)f2bf(v.w)<<16);
    *(uint2*)&xb[i] = u;
    return;
  }
  bid -= 8192;
  const float* src; u16* dst; int R, Cc, tc, tr;
  if (bid < 1024){        src=Wq; dst=WcatT;             R=1024; Cc=1024; int b=bid;      tc=(b&31)*32; tr=(b>>5)*32; }
  else if (bid < 2048){   src=Wk; dst=WcatT+1024*1024;   R=1024; Cc=1024; int b=bid-1024; tc=(b&31)*32; tr=(b>>5)*32; }
  else if (bid < 4096){   src=Wv; dst=WcatT+2048*1024;   R=1024; Cc=2048; int b=bid-2048; tc=(b&63)*32; tr=(b>>6)*32; }
  else if (bid < 6144){   src=Wg; dst=WcatT+4096*1024;   R=1024; Cc=2048; int b=bid-4096; tc=(b&63)*32; tr=(b>>6)*32; }
  else {                  src=Wo; dst=WoT;               R=2048; Cc=1024; int b=bid-6144; tc=(b&31)*32; tr=(b>>5)*32; }
  __shared__ float tile[32][33];
  int lr = threadIdx.x>>5, lc = threadIdx.x&31;
  #pragma unroll
  for (int p=0;p<4;p++)
    tile[lr+p*8][lc] = src[(size_t)(tr+lr+p*8)*Cc + tc + lc];
  __syncthreads();
  #pragma unroll
  for (int p=0;p<4;p++)
    dst[(size_t)(tc+lr+p*8)*R + tr + lc] = f2bf(tile[lc][lr+p*8]);
}

// =================================================================
// gemm1: 256x256 tile, BK=32, 8 waves, 4-buffer counted-vmcnt pipeline.
// Round 7: REVERT to the round-4 config (total 298.0us, best measured).
// Rounds 5/6 A/B-reproduced that the hot 128-tile gemm1 (48% VALU) wins
// -21us locally but costs +47us in downstream kernels (sustained-power/
// DVFS carry-over: governor time constant >> 0.3ms pipeline). Total is
// the objective -> 256-tile + XCD swizzle (FETCH 102->74MB verified).
// =================================================================
__global__ __launch_bounds__(512,1) void gemm1_256(const u16* __restrict__ A,
    const u16* __restrict__ BT, u16* __restrict__ C){
  __shared__ u16 L[4*16384];          // 4 x (A 8192 | B 8192) u16 = 128 KiB
  // XCD swizzle: flat in dispatch order; xcd = flat&7 (8 XCDs, round-robin)
  const int flat = blockIdx.y*24 + blockIdx.x;   // grid (24,32) = 768
  const int xcd  = flat & 7, loc = flat >> 3;    // loc in [0,96)
  const int bm   = xcd*4 + (loc & 3);            // [0,32): 4 A-panels per XCD, L2-resident
  const int bn   = loc >> 2;                     // [0,24): B streams
  const int t = threadIdx.x;          // 0..511
  const int w = t>>6, l = t&63;
  const int wm = w>>2, wn = w&3;      // 2M x 4N waves
  const int lr = l&15, lg = l>>4;
  const int srow = t>>2;              // 0..127 staging row within half
  const int gsw = ((t&3) - (t>>3)) & 3;   // inverse-swizzled source granule
  const size_t aoff = (size_t)(bm*256 + srow)*1024 + gsw*8;
  const size_t boff = (size_t)(bn*256 + srow)*1024 + gsw*8;
  const int sdo = t*8;

  u16 *p0 = L, *p1 = L+16384, *p2 = L+32768, *p3 = L+49152;

  auto STAGE = [&](u16* buf, int k0){
    __builtin_amdgcn_global_load_lds(&A[aoff + k0],                     buf + sdo,               16,0,0);
    __builtin_amdgcn_global_load_lds(&A[aoff + (size_t)128*1024 + k0],  buf + sdo + 4096,        16,0,0);
    __builtin_amdgcn_global_load_lds(&BT[boff + k0],                    buf + 8192 + sdo,        16,0,0);
    __builtin_amdgcn_global_load_lds(&BT[boff + (size_t)128*1024 + k0], buf + 8192 + sdo + 4096, 16,0,0);
  };

  f32x4 acc[8][4];
  #pragma unroll
  for (int m=0;m<8;m++)
    #pragma unroll
    for (int n=0;n<4;n++) acc[m][n] = (f32x4){0.f,0.f,0.f,0.f};

  STAGE(p0, 0); STAGE(p1, 32); STAGE(p2, 64);
  for (int kt=0; kt<32; ++kt){
    if      (kt < 30) asm volatile("s_waitcnt vmcnt(8)" ::: "memory");
    else if (kt == 30) asm volatile("s_waitcnt vmcnt(4)" ::: "memory");
    else               asm volatile("s_waitcnt vmcnt(0)" ::: "memory");
    __builtin_amdgcn_s_barrier();
    if (kt+3 < 32) STAGE(p3, (kt+3)*32);
    short8 af[8], bf4[4];
    #pragma unroll
    for (int m=0;m<8;m++){
      int row = wm*128 + m*16 + lr;
      af[m] = *(const short8*)(p0 + row*32 + (((lg + (row>>1))&3)<<3));
    }
    #pragma unroll
    for (int n=0;n<4;n++){
      int row = wn*64 + n*16 + lr;
      bf4[n] = *(const short8*)(p0 + 8192 + row*32 + (((lg + (row>>1))&3)<<3));
    }
    __builtin_amdgcn_s_setprio(1);
    #pragma unroll
    for (int m=0;m<8;m++)
      #pragma unroll
      for (int n=0;n<4;n++)
        acc[m][n] = MFMA16(af[m], bf4[n], acc[m][n]);
    __builtin_amdgcn_s_setprio(0);
    { u16* tp=p0; p0=p1; p1=p2; p2=p3; p3=tp; }
  }

  // ---- epilogue: LDS repack in 4 slabs of 64 rows, fused RoPE on q/k (verified r7) ----
  __syncthreads();
  const bool qk = (bn < 8);
  const float qscale = (bn < 4) ? 0.125f : 1.0f;   // DK^-0.5 folded into q
  #pragma unroll
  for (int s=0;s<4;++s){
    if (wm == (s>>1)){
      #pragma unroll
      for (int mm=0;mm<4;++mm){
        const int m = (s&1)*4 + mm;
        if (qk){
          #pragma unroll
          for (int n=0;n<2;n++){
            float inv = exp2f((float)(n*16+lr) * (-13.287712379549449f/32.0f)); // 10000^(-i/32)
            #pragma unroll
            for (int r=0;r<4;r++){
              int grow = bm*256 + wm*128 + m*16 + lg*4 + r;
              float f = (float)(grow & 4095) * inv;
              float sn, cs; __sincosf(f, &sn, &cs);
              float x1 = acc[m][n][r], x2 = acc[m][n+2][r];
              int lrow = mm*16 + lg*4 + r;
              L[lrow*264 + wn*64 + n*16 + lr]     = f2bf((x1*cs - x2*sn)*qscale);
              L[lrow*264 + wn*64 + (n+2)*16 + lr] = f2bf((x1*sn + x2*cs)*qscale);
            }
          }
        } else {
          #pragma unroll
          for (int n=0;n<4;n++)
            #pragma unroll
            for (int r=0;r<4;r++)
              L[(mm*16+lg*4+r)*264 + wn*64 + n*16 + lr] = f2bf(acc[m][n][r]);
        }
      }
    }
    __syncthreads();
    #pragma unroll
    for (int p=0;p<4;p++){
      int idx = p*512 + t;
      int row = idx>>5, gr = idx&31;
      *(short8*)&C[(size_t)(bm*256 + s*64 + row)*6144 + bn*256 + gr*8] =
        *(const short8*)&L[row*264 + gr*8];
    }
    __syncthreads();
  }
}

// ---------------- NT GEMM (gemm2): counted-vmcnt 3-buffer pipeline + granule swizzle ----------------
__global__ __launch_bounds__(256) void gemm2_nt(const u16* __restrict__ A,
    const u16* __restrict__ BT, float* __restrict__ C, int M, int N, int K){
  __shared__ u16 L[3*8192];
  // XCD swizzle: 512 blocks = 8 XCDs x (8 bm x 8 bn); WoT (4MB) + 8 A-panels per XCD
  const int flat = blockIdx.y*gridDim.x + blockIdx.x;
  const int xcd  = flat & 7, loc = flat >> 3;    // loc in [0,64)
  const int bm   = xcd*8 + (loc & 7);            // [0,64)
  const int bn   = loc >> 3;                     // [0,8)
  const int t = threadIdx.x;
  const int w = t>>6, l = t&63;
  const int wr = (w>>1)*64, wc = (w&1)*64;
  const int lr = l&15, lg = l>>4;
  const int srow = t>>2;
  const int gsw  = ((t&3) - (t>>3)) & 3;
  const int scol = gsw*8;
  const size_t aoff = (size_t)(bm*128 + srow)*K + scol;
  const size_t boff = (size_t)(bn*128 + srow)*K + scol;
  const int sdo = t*8;

  u16 *a0 = L,          *b0 = L + 4096;
  u16 *a1 = L + 8192,   *b1 = L + 12288;
  u16 *a2 = L + 16384,  *b2 = L + 20480;

  auto STAGE = [&](u16* la, u16* lb, int k0){
    __builtin_amdgcn_global_load_lds(&A[aoff + k0],                 la + sdo,        16, 0, 0);
    __builtin_amdgcn_global_load_lds(&A[aoff + (size_t)64*K + k0],  la + sdo + 2048, 16, 0, 0);
    __builtin_amdgcn_global_load_lds(&BT[boff + k0],                lb + sdo,        16, 0, 0);
    __builtin_amdgcn_global_load_lds(&BT[boff + (size_t)64*K + k0], lb + sdo + 2048, 16, 0, 0);
  };

  f32x4 acc[4][4];
  for (int m=0;m<4;m++) for (int n=0;n<4;n++) acc[m][n] = (f32x4){0.f,0.f,0.f,0.f};

  const int NT = K >> 5;
  STAGE(a0, b0, 0);
  STAGE(a1, b1, 32);
  for (int kt=0; kt<NT; ++kt){
    if (kt < NT-1) asm volatile("s_waitcnt vmcnt(4)" ::: "memory");
    else           asm volatile("s_waitcnt vmcnt(0)" ::: "memory");
    __builtin_amdgcn_s_barrier();
    if (kt+2 < NT) STAGE(a2, b2, (kt+2)*32);
    short8 af[4], bfr[4];
    #pragma unroll
    for (int m=0;m<4;m++){
      int rrow = wr + m*16 + lr;
      af[m]  = *(const short8*)(a0 + rrow*32 + (((lg + (rrow>>1))&3)<<3));
    }
    #pragma unroll
    for (int n=0;n<4;n++){
      int rrow = wc + n*16 + lr;
      bfr[n] = *(const short8*)(b0 + rrow*32 + (((lg + (rrow>>1))&3)<<3));
    }
    __builtin_amdgcn_s_setprio(1);
    #pragma unroll
    for (int m=0;m<4;m++)
      #pragma unroll
      for (int n=0;n<4;n++)
        acc[m][n] = MFMA16(af[m], bfr[n], acc[m][n]);
    __builtin_amdgcn_s_setprio(0);
    { u16* tp=a0; a0=a1; a1=a2; a2=tp; }
    { u16* tp=b0; b0=b1; b1=b2; b2=tp; }
  }

  #pragma unroll
  for (int m=0;m<4;m++)
    #pragma unroll
    for (int n=0;n<4;n++){
    int row = bm*128 + wr + m*16 + lg*4;
    int col = bn*128 + wc + n*16 + lr;
    #pragma unroll
    for (int r=0;r<4;r++)
      C[(size_t)(row+r)*N + col] = acc[m][n][r];
  }
}

// ---------------- retention pass 1: XOR-granule-swizzled kT/vT, decay table ----------------
__global__ __launch_bounds__(256) void retention_r1(const u16* __restrict__ qkvg,
    u16* __restrict__ o, u16* __restrict__ states){
  int bid = blockIdx.x;                 // ((b*16+h)*64 + c)
  int c = bid & 63, h = (bid>>6)&15, b = bid>>10;
  int t = threadIdx.x, w = t>>6, l = t&63, lr = l&15, lg = l>>4;
  __shared__ u16 SH[17280];             // kT[64][64] | vT[128][64] | A_lds[64][72]; reused by epilogue
  __shared__ float pw[72];              // gamma^delta
  u16* kT    = SH;                      // granule-swizzled: g' = g ^ ((row>>3)&7)
  u16* vT    = SH + 4096;
  u16* A_lds = SH + 12288;              // [64][72] unswizzled
  float log2g = log2f(1.0f - exp2f(-5.0f - (float)h));
  if (t < 65) pw[t] = exp2f(log2g*(float)t);
  const size_t rowbase = (size_t)(b*4096 + c*64);
  __syncthreads();

  // stage + transpose k, v into LDS (paired u32 writes, XOR-granule swizzle)
  {
    int rp = t>>3, cg = t&7;            // k: 32 row-pairs x 8 col-groups
    int r0 = rp*2;
    short8 k0v = *(const short8*)&qkvg[(rowbase+r0  )*6144 + 1024 + h*64 + cg*8];
    short8 k1v = *(const short8*)&qkvg[(rowbase+r0+1)*6144 + 1024 + h*64 + cg*8];
    float d0 = pw[63-r0], d1 = pw[62-r0];
    #pragma unroll
    for (int j=0;j<8;j++){
      int d = cg*8+j;
      uint32_t pk = (uint32_t)f2bf(bf2f((u16)k0v[j])*d0) | ((uint32_t)f2bf(bf2f((u16)k1v[j])*d1)<<16);
      *(uint32_t*)&kT[d*64 + (((r0>>3) ^ (d>>3))<<3) + (r0&7)] = pk;
    }
    #pragma unroll
    for (int p=0;p<2;p++){              // v: 32 row-pairs x 16 col-groups
      int it = t + p*256;
      int vrp = it>>4, vcg = it&15;
      int vr0 = vrp*2;
      short8 v0 = *(const short8*)&qkvg[(rowbase+vr0  )*6144 + 2048 + h*128 + vcg*8];
      short8 v1 = *(const short8*)&qkvg[(rowbase+vr0+1)*6144 + 2048 + h*128 + vcg*8];
      #pragma unroll
      for (int j=0;j<8;j++){
        int e = vcg*8+j;
        uint32_t pv = (uint32_t)(u16)v0[j] | ((uint32_t)(u16)v1[j]<<16);
        *(uint32_t*)&vT[e*64 + (((vr0>>3) ^ ((e>>3)&7))<<3) + (vr0&7)] = pv;
      }
    }
  }

  // A = q @ k^T
  f32x4 z4 = {0.f,0.f,0.f,0.f};
  f32x4 accA[4] = {z4,z4,z4,z4};
  #pragma unroll
  for (int ks=0;ks<2;ks++){
    short8 aq = *(const short8*)&qkvg[(rowbase + w*16+lr)*6144 + h*64 + ks*32 + lg*8];
    #pragma unroll
    for (int n=0;n<4;n++){
      short8 bk = *(const short8*)&qkvg[(rowbase + n*16+lr)*6144 + 1024 + h*64 + ks*32 + lg*8];
      accA[n] = MFMA16(aq, bk, accA[n]);
    }
  }
  #pragma unroll
  for (int n=0;n<4;n++)
    #pragma unroll
    for (int r=0;r<4;r++){
    int i = w*16 + lg*4 + r, j = n*16 + lr;
    float v = (i>=j) ? accA[n][r]*pw[i-j] : 0.0f;
    A_lds[i*72 + j] = f2bf(v);
  }
  __syncthreads();

  // o_intra = A @ v ; S_c = kdT @ v   (swizzled granule reads: broadcast, conflict-free)
  f32x4 accO[8], accS[8];
  #pragma unroll
  for (int n=0;n<8;n++){ accO[n]=z4; accS[n]=z4; }
  #pragma unroll
  for (int ks=0;ks<2;ks++){
    int rk = w*16+lr;
    short8 aA = *(const short8*)&A_lds[rk*72 + ks*32+lg*8];
    short8 aK = *(const short8*)&kT[rk*64 + (((ks*4+lg) ^ (rk>>3))<<3)];
    #pragma unroll
    for (int n=0;n<8;n++){
      int e2 = n*16+lr;
      short8 bv = *(const short8*)&vT[e2*64 + (((ks*4+lg) ^ ((e2>>3)&7))<<3)];
      accO[n] = MFMA16(aA, bv, accO[n]);
      accS[n] = MFMA16(aK, bv, accS[n]);
    }
  }

  // -------- coalesced epilogue: repack via LDS --------
  __syncthreads();
  u16* oB = SH;                          // [64][132]
  u16* sB = SH + 8448;                   // [128][68]
  #pragma unroll
  for (int n=0;n<8;n++)
    #pragma unroll
    for (int r=0;r<4;r++){
    int i = w*16 + lg*4 + r, e = n*16 + lr;
    oB[i*132 + e] = f2bf(accO[n][r]);
    sB[e*68 + i]  = f2bf(accS[n][r]);
  }
  __syncthreads();
  const size_t ob = rowbase*2048 + h*128;
  const size_t sb = ((size_t)(b*16+h)*64 + c)*8192;   // states[b][h][c][e=128][d=64]
  {
    int orow = t>>2, ocol = (t&3)*32;
    #pragma unroll
    for (int q=0;q<4;q++)
      *(short8*)&o[ob + (size_t)orow*2048 + ocol + q*8] = *(const short8*)&oB[orow*132 + ocol + q*8];
    int se = t>>1, sd = (t&1)*32;
    #pragma unroll
    for (int q=0;q<4;q++)
      *(short8*)&states[sb + (size_t)se*64 + sd + q*8] = *(const short8*)&sB[se*68 + sd + q*8];
  }
}

// ---------------- retention pass 2: scan over chunks, o += (q*dq) @ S ----------------
__global__ __launch_bounds__(256) void retention_r2(const u16* __restrict__ qkvg,
    const u16* __restrict__ states, u16* __restrict__ o){
  int bid = blockIdx.x;
  int vblk = bid & 7, h = (bid>>3)&15, b = bid>>7;
  int t = threadIdx.x, w = t>>6, l = t&63, lr = l&15, lg = l>>4;
  int e0 = vblk*16;
  float log2g = log2f(1.0f - exp2f(-5.0f - (float)h));
  float gC = exp2f(64.0f*log2g);
  float dqv[4];
  #pragma unroll
  for (int r=0;r<4;r++) dqv[r] = exp2f(log2g*(float)(w*16 + lg*4 + r + 1));
  float st[16];
  #pragma unroll
  for (int i=0;i<16;i++) st[i]=0.f;
  const size_t sbase = ((size_t)(b*16+h)*64)*8192 + (size_t)(e0+lr)*64 + lg*8;
  const size_t qb = (size_t)(b*4096)*6144 + h*64 + (size_t)(w*16+lr)*6144 + lg*8;
  const size_t obh = (size_t)(b*4096)*2048 + h*128 + e0 + lr;
  short8 nsc0 = *(const short8*)&states[sbase];
  short8 nsc1 = *(const short8*)&states[sbase + 32];
  short8 naq0 = *(const short8*)&qkvg[qb];
  short8 naq1 = *(const short8*)&qkvg[qb + 32];
  for (int c=0;c<64;c++){
    short8 sc0 = nsc0, sc1 = nsc1, aq0 = naq0, aq1 = naq1;
    if (c < 63){
      nsc0 = *(const short8*)&states[sbase + (size_t)(c+1)*8192];
      nsc1 = *(const short8*)&states[sbase + (size_t)(c+1)*8192 + 32];
      naq0 = *(const short8*)&qkvg[qb + (size_t)(c+1)*64*6144];
      naq1 = *(const short8*)&qkvg[qb + (size_t)(c+1)*64*6144 + 32];
    }
    f32x4 acc = {0.f,0.f,0.f,0.f};
    short8 bs0, bs1;
    #pragma unroll
    for (int dd=0;dd<8;dd++) bs0[dd] = (short)f2bf(st[dd]);
    #pragma unroll
    for (int dd=0;dd<8;dd++) bs1[dd] = (short)f2bf(st[dd+8]);
    acc = MFMA16(aq0, bs0, acc);
    acc = MFMA16(aq1, bs1, acc);
    #pragma unroll
    for (int r=0;r<4;r++){
      int i = w*16 + lg*4 + r;
      size_t oi = obh + (size_t)(c*64 + i)*2048;
      o[oi] = f2bf(bf2f(o[oi]) + dqv[r]*acc[r]);
    }
    #pragma unroll
    for (int i2=0;i2<8;i2++) st[i2]   = gC*st[i2]   + bf2f((u16)sc0[i2]);
    #pragma unroll
    for (int i2=0;i2<8;i2++) st[i2+8] = gC*st[i2+8] + bf2f((u16)sc1[i2]);
  }
}

// ---------------- fused RMSNorm (over DV=128) + swish gate -> bf16 ----------------
// Round 7: vectorized (G13). 16 lanes per (row,head), short8 (16B) loads,
// 8 elems/thread, shfl_xor 8/4/2/1 reduction within aligned 16-lane groups.
__global__ __launch_bounds__(256) void norm_gate(const u16* __restrict__ o,
    const u16* __restrict__ qkvg, const float* __restrict__ gnw, u16* __restrict__ og){
  int g16 = threadIdx.x >> 4;          // 16 groups per block
  int l16 = threadIdx.x & 15;          // lane within group
  int rowh = blockIdx.x*16 + g16;
  int row = rowh >> 4, h = rowh & 15;
  short8 vv = *(const short8*)(o + (size_t)row*2048 + h*128 + l16*8);
  float v[8];
  float ss = 0.f;
  #pragma unroll
  for (int j=0;j<8;j++){ v[j] = bf2f((u16)vv[j]); ss += v[j]*v[j]; }
  #pragma unroll
  for (int off=8; off; off>>=1) ss += __shfl_xor(ss, off);
  float rs = rsqrtf(ss*(1.0f/128.0f) + 1e-5f);
  short8 gg = *(const short8*)(qkvg + (size_t)row*6144 + 4096 + h*128 + l16*8);
  float4 w0 = *(const float4*)&gnw[l16*8];
  float4 w1 = *(const float4*)&gnw[l16*8 + 4];
  float wv[8] = {w0.x,w0.y,w0.z,w0.w,w1.x,w1.y,w1.z,w1.w};
  short8 res;
  #pragma unroll
  for (int j=0;j<8;j++){
    float gj = bf2f((u16)gg[j]);
    float rj = v[j]*rs*wv[j] * (gj/(1.f+expf(-gj)));
    res[j] = (short)f2bf(rj);
  }
  *(short8*)(og + (size_t)row*2048 + h*128 + l16*8) = res;
}

extern "C" void kernel_launch(void* const* d_in, const int* in_sizes, int n_in,
                              void* d_out, int out_size, void* d_ws, size_t ws_size,
                              hipStream_t stream){
  const float* x   = (const float*)d_in[0];
  const float* Wq  = (const float*)d_in[1];
  const float* Wk  = (const float*)d_in[2];
  const float* Wv  = (const float*)d_in[3];
  const float* Wg  = (const float*)d_in[4];
  const float* Wo  = (const float*)d_in[5];
  const float* gnw = (const float*)d_in[6];
  float* out = (float*)d_out;

  const size_t NEED = 171966464ull;    // 164 MB
  if (ws_size < NEED) return;

  char* base = (char*)d_ws;
  u16* qkvg  = (u16*)(base);                 // [8192][6144] bf16            [0,96M)
  u16* obuf  = (u16*)(base + 100663296);     // [8192][2048] bf16            [96M,128M)
  u16* WoT   = (u16*)(base + 134217728);     // [1024][2048] bf16            [128M,132M)
  u16* xb    = (u16*)(base + 138412032);     // [8192][1024] bf16            dead after gemm1
  u16* WcatT = (u16*)(base + 155189248);     // [6144][1024] bf16            dead after gemm1
  u16* stt   = (u16*)(base + 138412032);     // [B][H][64][128][64] bf16     alias, live r1->r2
  u16* og    = (u16*)(base + 138412032);     // [8192][2048] bf16            alias, live ng->gemm2

  prep<<<16384,256,0,stream>>>(x, xb, Wq, Wk, Wv, Wg, Wo, WcatT, WoT);
  gemm1_256<<<dim3(24,32),512,0,stream>>>(xb, WcatT, qkvg);
  retention_r1<<<2048,256,0,stream>>>(qkvg, obuf, stt);
  retention_r2<<<256,256,0,stream>>>(qkvg, stt, obuf);
  norm_gate<<<8192,256,0,stream>>>(obuf, qkvg, gnw, og);
  gemm2_nt<<<dim3(8,64),256,0,stream>>>(og, WoT, out, 8192, 1024, 2048);
}

// Round 8
// 287.619 us; speedup vs baseline: 1.1275x; 1.0184x over previous
//
#include <hip/hip_runtime.h>
#include <stdint.h>
#include <type_traits>

typedef unsigned short u16;
typedef __attribute__((ext_vector_type(8))) short short8;
typedef __attribute__((ext_vector_type(4))) float f32x4;

#define MFMA16(a,b,c) __builtin_amdgcn_mfma_f32_16x16x32_bf16(a,b,c,0,0,0)

__device__ __forceinline__ u16 f2bf(float f){
  uint32_t u = __builtin_bit_cast(uint32_t, f);
  u += 0x7FFFu + ((u>>16)&1u);
  return (u16)(u>>16);
}
__device__ __forceinline__ float bf2f(u16 h){
  uint32_t u = ((uint32_t)h)<<16;
  return __builtin_bit_cast(float, u);
}

// ---------------- prep: cast x f32->bf16 (bid<8192) + all weight transposes ----------------
__global__ __launch_bounds__(256) void prep(const float* __restrict__ x, u16* __restrict__ xb,
    const float* __restrict__ Wq, const float* __restrict__ Wk, const float* __restrict__ Wv,
    const float* __restrict__ Wg, const float* __restrict__ Wo,
    u16* __restrict__ WcatT, u16* __restrict__ WoT){
  int bid = blockIdx.x;
  if (bid < 8192){
    int i = (bid*256 + threadIdx.x)*4;
    float4 v = *(const float4*)&x[i];
    uint2 u;
    u.x = (uint32_t)f2bf(v.x) | ((uint32_t)f2bf(v.y)<<16);
    u.y = (uint32_t)f2bf(v.z) | ((uint32_t)f2bf(v.w)<<16);
    *(uint2*)&xb[i] = u;
    return;
  }
  bid -= 8192;
  const float* src; u16* dst; int R, Cc, tc, tr;
  if (bid < 1024){        src=Wq; dst=WcatT;             R=1024; Cc=1024; int b=bid;      tc=(b&31)*32; tr=(b>>5)*32; }
  else if (bid < 2048){   src=Wk; dst=WcatT+1024*1024;   R=1024; Cc=1024; int b=bid-1024; tc=(b&31)*32; tr=(b>>5)*32; }
  else if (bid < 4096){   src=Wv; dst=WcatT+2048*1024;   R=1024; Cc=2048; int b=bid-2048; tc=(b&63)*32; tr=(b>>6)*32; }
  else if (bid < 6144){   src=Wg; dst=WcatT+4096*1024;   R=1024; Cc=2048; int b=bid-4096; tc=(b&63)*32; tr=(b>>6)*32; }
  else {                  src=Wo; dst=WoT;               R=2048; Cc=1024; int b=bid-6144; tc=(b&31)*32; tr=(b>>5)*32; }
  __shared__ float tile[32][33];
  int lr = threadIdx.x>>5, lc = threadIdx.x&31;
  #pragma unroll
  for (int p=0;p<4;p++)
    tile[lr+p*8][lc] = src[(size_t)(tr+lr+p*8)*Cc + tc + lc];
  __syncthreads();
  #pragma unroll
  for (int p=0;p<4;p++)
    dst[(size_t)(tc+lr+p*8)*R + tr + lc] = f2bf(tile[lc][lr+p*8]);
}

// =================================================================
// gemm1: 256x256 tile, BK=32, 8 waves, 4-buffer counted-vmcnt pipeline.
// Round 8: m201-style 2-phase READ-AHEAD, 1 barrier/kt. Cycle audit of the
// r7 loop: 4175 cyc/kt vs MFMA 1240 + LDS 1150 + stage 256 — the reads and
// MFMA serialize (read all 12 -> drain -> 32 MFMA). New schedule rides the
// reads under the MFMA clusters:
//   top:  read afB(kt) [4 ds] under MFMA-A(kt) (uses afA/bf4 from prev it)
//         STAGE(kt+3)
//   mid:  lgkm(0) + counted vmcnt(8/4/0) + s_barrier  (validates buf kt+1;
//         lgkm drain restores read-complete-before-barrier for stage safety)
//   post: read afA(kt+1)+bf4n(kt+1) from p1 [8 ds] under MFMA-B(kt)
// No unroll, scalar 4-reg copy for bf4 double-buffer (r1 spill lesson).
// + XCD swizzle (FETCH 102->74MB verified) + fused RoPE epilogue.
// =================================================================
__global__ __launch_bounds__(512,1) void gemm1_256(const u16* __restrict__ A,
    const u16* __restrict__ BT, u16* __restrict__ C){
  __shared__ u16 L[4*16384];          // 4 x (A 8192 | B 8192) u16 = 128 KiB
  const int flat = blockIdx.y*24 + blockIdx.x;   // grid (24,32) = 768
  const int xcd  = flat & 7, loc = flat >> 3;    // loc in [0,96)
  const int bm   = xcd*4 + (loc & 3);            // [0,32): 4 A-panels per XCD, L2-resident
  const int bn   = loc >> 2;                     // [0,24): B streams
  const int t = threadIdx.x;          // 0..511
  const int w = t>>6, l = t&63;
  const int wm = w>>2, wn = w&3;      // 2M x 4N waves
  const int lr = l&15, lg = l>>4;
  const int srow = t>>2;              // 0..127 staging row within half
  const int gsw = ((t&3) - (t>>3)) & 3;   // inverse-swizzled source granule
  const size_t aoff = (size_t)(bm*256 + srow)*1024 + gsw*8;
  const size_t boff = (size_t)(bn*256 + srow)*1024 + gsw*8;
  const int sdo = t*8;

  u16 *p0 = L, *p1 = L+16384, *p2 = L+32768, *p3 = L+49152;

  auto STAGE = [&](u16* buf, int k0){
    __builtin_amdgcn_global_load_lds(&A[aoff + k0],                     buf + sdo,               16,0,0);
    __builtin_amdgcn_global_load_lds(&A[aoff + (size_t)128*1024 + k0],  buf + sdo + 4096,        16,0,0);
    __builtin_amdgcn_global_load_lds(&BT[boff + k0],                    buf + 8192 + sdo,        16,0,0);
    __builtin_amdgcn_global_load_lds(&BT[boff + (size_t)128*1024 + k0], buf + 8192 + sdo + 4096, 16,0,0);
  };
  auto LDA = [&](const u16* base, int row)->short8 {
    return *(const short8*)(base + row*32 + (((lg + (row>>1))&3)<<3));
  };

  f32x4 acc[8][4];
  #pragma unroll
  for (int m=0;m<8;m++)
    #pragma unroll
    for (int n=0;n<4;n++) acc[m][n] = (f32x4){0.f,0.f,0.f,0.f};

  STAGE(p0, 0); STAGE(p1, 32); STAGE(p2, 64);
  // prologue: p0 resident for ALL waves (vmcnt covers own loads; barrier covers peers)
  asm volatile("s_waitcnt vmcnt(8)" ::: "memory");
  __builtin_amdgcn_s_barrier();
  short8 afA[4], afB[4], bf4[4], bf4n[4];
  #pragma unroll
  for (int m=0;m<4;m++) afA[m] = LDA(p0, wm*128 + m*16 + lr);
  #pragma unroll
  for (int n=0;n<4;n++) bf4[n] = LDA(p0 + 8192, wn*64 + n*16 + lr);

  for (int kt=0; kt<32; ++kt){
    // ---- phase A: read afB(kt) under MFMA-A(kt); issue stage kt+3 ----
    #pragma unroll
    for (int m=0;m<4;m++) afB[m] = LDA(p0, wm*128 + (m+4)*16 + lr);
    if (kt+3 < 32) STAGE(p3, (kt+3)*32);
    __builtin_amdgcn_s_setprio(1);
    #pragma unroll
    for (int m=0;m<4;m++)
      #pragma unroll
      for (int n=0;n<4;n++)
        acc[m][n] = MFMA16(afA[m], bf4[n], acc[m][n]);
    __builtin_amdgcn_s_setprio(0);
    // ---- mid: single barrier per kt. lgkm(0): all p0 reads complete (stage
    // safety); vmcnt(N): buf(kt+1) staged for this wave; barrier: for all waves.
    asm volatile("s_waitcnt lgkmcnt(0)" ::: "memory");
    __builtin_amdgcn_sched_barrier(0);
    if      (kt < 29)  asm volatile("s_waitcnt vmcnt(8)" ::: "memory");
    else if (kt == 29) asm volatile("s_waitcnt vmcnt(4)" ::: "memory");
    else               asm volatile("s_waitcnt vmcnt(0)" ::: "memory");
    __builtin_amdgcn_s_barrier();
    __builtin_amdgcn_sched_barrier(0);
    // ---- phase B: read afA/bf4n(kt+1) from p1 under MFMA-B(kt) ----
    if (kt+1 < 32){
      #pragma unroll
      for (int m=0;m<4;m++) afA[m]  = LDA(p1, wm*128 + m*16 + lr);
      #pragma unroll
      for (int n=0;n<4;n++) bf4n[n] = LDA(p1 + 8192, wn*64 + n*16 + lr);
    }
    __builtin_amdgcn_s_setprio(1);
    #pragma unroll
    for (int m=0;m<4;m++)
      #pragma unroll
      for (int n=0;n<4;n++)
        acc[m+4][n] = MFMA16(afB[m], bf4[n], acc[m+4][n]);
    __builtin_amdgcn_s_setprio(0);
    if (kt+1 < 32){
      #pragma unroll
      for (int n=0;n<4;n++) bf4[n] = bf4n[n];
    }
    { u16* tp=p0; p0=p1; p1=p2; p2=p3; p3=tp; }
  }

  // ---- epilogue: LDS repack in 4 slabs of 64 rows, fused RoPE on q/k (verified r7) ----
  __syncthreads();
  const bool qk = (bn < 8);
  const float qscale = (bn < 4) ? 0.125f : 1.0f;   // DK^-0.5 folded into q
  #pragma unroll
  for (int s=0;s<4;++s){
    if (wm == (s>>1)){
      #pragma unroll
      for (int mm=0;mm<4;++mm){
        const int m = (s&1)*4 + mm;
        if (qk){
          #pragma unroll
          for (int n=0;n<2;n++){
            float inv = exp2f((float)(n*16+lr) * (-13.287712379549449f/32.0f)); // 10000^(-i/32)
            #pragma unroll
            for (int r=0;r<4;r++){
              int grow = bm*256 + wm*128 + m*16 + lg*4 + r;
              float f = (float)(grow & 4095) * inv;
              float sn, cs; __sincosf(f, &sn, &cs);
              float x1 = acc[m][n][r], x2 = acc[m][n+2][r];
              int lrow = mm*16 + lg*4 + r;
              L[lrow*264 + wn*64 + n*16 + lr]     = f2bf((x1*cs - x2*sn)*qscale);
              L[lrow*264 + wn*64 + (n+2)*16 + lr] = f2bf((x1*sn + x2*cs)*qscale);
            }
          }
        } else {
          #pragma unroll
          for (int n=0;n<4;n++)
            #pragma unroll
            for (int r=0;r<4;r++)
              L[(mm*16+lg*4+r)*264 + wn*64 + n*16 + lr] = f2bf(acc[m][n][r]);
        }
      }
    }
    __syncthreads();
    #pragma unroll
    for (int p=0;p<4;p++){
      int idx = p*512 + t;
      int row = idx>>5, gr = idx&31;
      *(short8*)&C[(size_t)(bm*256 + s*64 + row)*6144 + bn*256 + gr*8] =
        *(const short8*)&L[row*264 + gr*8];
    }
    __syncthreads();
  }
}

// ---------------- NT GEMM (gemm2): counted-vmcnt 3-buffer pipeline + granule swizzle ----------------
__global__ __launch_bounds__(256) void gemm2_nt(const u16* __restrict__ A,
    const u16* __restrict__ BT, float* __restrict__ C, int M, int N, int K){
  __shared__ u16 L[3*8192];
  // XCD swizzle: 512 blocks = 8 XCDs x (8 bm x 8 bn); WoT (4MB) + 8 A-panels per XCD
  const int flat = blockIdx.y*gridDim.x + blockIdx.x;
  const int xcd  = flat & 7, loc = flat >> 3;    // loc in [0,64)
  const int bm   = xcd*8 + (loc & 7);            // [0,64)
  const int bn   = loc >> 3;                     // [0,8)
  const int t = threadIdx.x;
  const int w = t>>6, l = t&63;
  const int wr = (w>>1)*64, wc = (w&1)*64;
  const int lr = l&15, lg = l>>4;
  const int srow = t>>2;
  const int gsw  = ((t&3) - (t>>3)) & 3;
  const int scol = gsw*8;
  const size_t aoff = (size_t)(bm*128 + srow)*K + scol;
  const size_t boff = (size_t)(bn*128 + srow)*K + scol;
  const int sdo = t*8;

  u16 *a0 = L,          *b0 = L + 4096;
  u16 *a1 = L + 8192,   *b1 = L + 12288;
  u16 *a2 = L + 16384,  *b2 = L + 20480;

  auto STAGE = [&](u16* la, u16* lb, int k0){
    __builtin_amdgcn_global_load_lds(&A[aoff + k0],                 la + sdo,        16, 0, 0);
    __builtin_amdgcn_global_load_lds(&A[aoff + (size_t)64*K + k0],  la + sdo + 2048, 16, 0, 0);
    __builtin_amdgcn_global_load_lds(&BT[boff + k0],                lb + sdo,        16, 0, 0);
    __builtin_amdgcn_global_load_lds(&BT[boff + (size_t)64*K + k0], lb + sdo + 2048, 16, 0, 0);
  };

  f32x4 acc[4][4];
  for (int m=0;m<4;m++) for (int n=0;n<4;n++) acc[m][n] = (f32x4){0.f,0.f,0.f,0.f};

  const int NT = K >> 5;
  STAGE(a0, b0, 0);
  STAGE(a1, b1, 32);
  for (int kt=0; kt<NT; ++kt){
    if (kt < NT-1) asm volatile("s_waitcnt vmcnt(4)" ::: "memory");
    else           asm volatile("s_waitcnt vmcnt(0)" ::: "memory");
    __builtin_amdgcn_s_barrier();
    if (kt+2 < NT) STAGE(a2, b2, (kt+2)*32);
    short8 af[4], bfr[4];
    #pragma unroll
    for (int m=0;m<4;m++){
      int rrow = wr + m*16 + lr;
      af[m]  = *(const short8*)(a0 + rrow*32 + (((lg + (rrow>>1))&3)<<3));
    }
    #pragma unroll
    for (int n=0;n<4;n++){
      int rrow = wc + n*16 + lr;
      bfr[n] = *(const short8*)(b0 + rrow*32 + (((lg + (rrow>>1))&3)<<3));
    }
    __builtin_amdgcn_s_setprio(1);
    #pragma unroll
    for (int m=0;m<4;m++)
      #pragma unroll
      for (int n=0;n<4;n++)
        acc[m][n] = MFMA16(af[m], bfr[n], acc[m][n]);
    __builtin_amdgcn_s_setprio(0);
    { u16* tp=a0; a0=a1; a1=a2; a2=tp; }
    { u16* tp=b0; b0=b1; b1=b2; b2=tp; }
  }

  #pragma unroll
  for (int m=0;m<4;m++)
    #pragma unroll
    for (int n=0;n<4;n++){
    int row = bm*128 + wr + m*16 + lg*4;
    int col = bn*128 + wc + n*16 + lr;
    #pragma unroll
    for (int r=0;r<4;r++)
      C[(size_t)(row+r)*N + col] = acc[m][n][r];
  }
}

// ---------------- retention pass 1: XOR-granule-swizzled kT/vT, decay table ----------------
__global__ __launch_bounds__(256) void retention_r1(const u16* __restrict__ qkvg,
    u16* __restrict__ o, u16* __restrict__ states){
  int bid = blockIdx.x;                 // ((b*16+h)*64 + c)
  int c = bid & 63, h = (bid>>6)&15, b = bid>>10;
  int t = threadIdx.x, w = t>>6, l = t&63, lr = l&15, lg = l>>4;
  __shared__ u16 SH[17280];             // kT[64][64] | vT[128][64] | A_lds[64][72]; reused by epilogue
  __shared__ float pw[72];              // gamma^delta
  u16* kT    = SH;                      // granule-swizzled: g' = g ^ ((row>>3)&7)
  u16* vT    = SH + 4096;
  u16* A_lds = SH + 12288;              // [64][72] unswizzled
  float log2g = log2f(1.0f - exp2f(-5.0f - (float)h));
  if (t < 65) pw[t] = exp2f(log2g*(float)t);
  const size_t rowbase = (size_t)(b*4096 + c*64);
  __syncthreads();

  // stage + transpose k, v into LDS (paired u32 writes, XOR-granule swizzle)
  {
    int rp = t>>3, cg = t&7;            // k: 32 row-pairs x 8 col-groups
    int r0 = rp*2;
    short8 k0v = *(const short8*)&qkvg[(rowbase+r0  )*6144 + 1024 + h*64 + cg*8];
    short8 k1v = *(const short8*)&qkvg[(rowbase+r0+1)*6144 + 1024 + h*64 + cg*8];
    float d0 = pw[63-r0], d1 = pw[62-r0];
    #pragma unroll
    for (int j=0;j<8;j++){
      int d = cg*8+j;
      uint32_t pk = (uint32_t)f2bf(bf2f((u16)k0v[j])*d0) | ((uint32_t)f2bf(bf2f((u16)k1v[j])*d1)<<16);
      *(uint32_t*)&kT[d*64 + (((r0>>3) ^ (d>>3))<<3) + (r0&7)] = pk;
    }
    #pragma unroll
    for (int p=0;p<2;p++){              // v: 32 row-pairs x 16 col-groups
      int it = t + p*256;
      int vrp = it>>4, vcg = it&15;
      int vr0 = vrp*2;
      short8 v0 = *(const short8*)&qkvg[(rowbase+vr0  )*6144 + 2048 + h*128 + vcg*8];
      short8 v1 = *(const short8*)&qkvg[(rowbase+vr0+1)*6144 + 2048 + h*128 + vcg*8];
      #pragma unroll
      for (int j=0;j<8;j++){
        int e = vcg*8+j;
        uint32_t pv = (uint32_t)(u16)v0[j] | ((uint32_t)(u16)v1[j]<<16);
        *(uint32_t*)&vT[e*64 + (((vr0>>3) ^ ((e>>3)&7))<<3) + (vr0&7)] = pv;
      }
    }
  }

  // A = q @ k^T
  f32x4 z4 = {0.f,0.f,0.f,0.f};
  f32x4 accA[4] = {z4,z4,z4,z4};
  #pragma unroll
  for (int ks=0;ks<2;ks++){
    short8 aq = *(const short8*)&qkvg[(rowbase + w*16+lr)*6144 + h*64 + ks*32 + lg*8];
    #pragma unroll
    for (int n=0;n<4;n++){
      short8 bk = *(const short8*)&qkvg[(rowbase + n*16+lr)*6144 + 1024 + h*64 + ks*32 + lg*8];
      accA[n] = MFMA16(aq, bk, accA[n]);
    }
  }
  #pragma unroll
  for (int n=0;n<4;n++)
    #pragma unroll
    for (int r=0;r<4;r++){
    int i = w*16 + lg*4 + r, j = n*16 + lr;
    float v = (i>=j) ? accA[n][r]*pw[i-j] : 0.0f;
    A_lds[i*72 + j] = f2bf(v);
  }
  __syncthreads();

  // o_intra = A @ v ; S_c = kdT @ v   (swizzled granule reads: broadcast, conflict-free)
  f32x4 accO[8], accS[8];
  #pragma unroll
  for (int n=0;n<8;n++){ accO[n]=z4; accS[n]=z4; }
  #pragma unroll
  for (int ks=0;ks<2;ks++){
    int rk = w*16+lr;
    short8 aA = *(const short8*)&A_lds[rk*72 + ks*32+lg*8];
    short8 aK = *(const short8*)&kT[rk*64 + (((ks*4+lg) ^ (rk>>3))<<3)];
    #pragma unroll
    for (int n=0;n<8;n++){
      int e2 = n*16+lr;
      short8 bv = *(const short8*)&vT[e2*64 + (((ks*4+lg) ^ ((e2>>3)&7))<<3)];
      accO[n] = MFMA16(aA, bv, accO[n]);
      accS[n] = MFMA16(aK, bv, accS[n]);
    }
  }

  // -------- coalesced epilogue: repack via LDS --------
  __syncthreads();
  u16* oB = SH;                          // [64][132]
  u16* sB = SH + 8448;                   // [128][68]
  #pragma unroll
  for (int n=0;n<8;n++)
    #pragma unroll
    for (int r=0;r<4;r++){
    int i = w*16 + lg*4 + r, e = n*16 + lr;
    oB[i*132 + e] = f2bf(accO[n][r]);
    sB[e*68 + i]  = f2bf(accS[n][r]);
  }
  __syncthreads();
  const size_t ob = rowbase*2048 + h*128;
  const size_t sb = ((size_t)(b*16+h)*64 + c)*8192;   // states[b][h][c][e=128][d=64]
  {
    int orow = t>>2, ocol = (t&3)*32;
    #pragma unroll
    for (int q=0;q<4;q++)
      *(short8*)&o[ob + (size_t)orow*2048 + ocol + q*8] = *(const short8*)&oB[orow*132 + ocol + q*8];
    int se = t>>1, sd = (t&1)*32;
    #pragma unroll
    for (int q=0;q<4;q++)
      *(short8*)&states[sb + (size_t)se*64 + sd + q*8] = *(const short8*)&sB[se*68 + sd + q*8];
  }
}

// ---------------- retention pass 2: scan over chunks, o += (q*dq) @ S ----------------
__global__ __launch_bounds__(256) void retention_r2(const u16* __restrict__ qkvg,
    const u16* __restrict__ states, u16* __restrict__ o){
  int bid = blockIdx.x;
  int vblk = bid & 7, h = (bid>>3)&15, b = bid>>7;
  int t = threadIdx.x, w = t>>6, l = t&63, lr = l&15, lg = l>>4;
  int e0 = vblk*16;
  float log2g = log2f(1.0f - exp2f(-5.0f - (float)h));
  float gC = exp2f(64.0f*log2g);
  float dqv[4];
  #pragma unroll
  for (int r=0;r<4;r++) dqv[r] = exp2f(log2g*(float)(w*16 + lg*4 + r + 1));
  float st[16];
  #pragma unroll
  for (int i=0;i<16;i++) st[i]=0.f;
  const size_t sbase = ((size_t)(b*16+h)*64)*8192 + (size_t)(e0+lr)*64 + lg*8;
  const size_t qb = (size_t)(b*4096)*6144 + h*64 + (size_t)(w*16+lr)*6144 + lg*8;
  const size_t obh = (size_t)(b*4096)*2048 + h*128 + e0 + lr;
  short8 nsc0 = *(const short8*)&states[sbase];
  short8 nsc1 = *(const short8*)&states[sbase + 32];
  short8 naq0 = *(const short8*)&qkvg[qb];
  short8 naq1 = *(const short8*)&qkvg[qb + 32];
  for (int c=0;c<64;c++){
    short8 sc0 = nsc0, sc1 = nsc1, aq0 = naq0, aq1 = naq1;
    if (c < 63){
      nsc0 = *(const short8*)&states[sbase + (size_t)(c+1)*8192];
      nsc1 = *(const short8*)&states[sbase + (size_t)(c+1)*8192 + 32];
      naq0 = *(const short8*)&qkvg[qb + (size_t)(c+1)*64*6144];
      naq1 = *(const short8*)&qkvg[qb + (size_t)(c+1)*64*6144 + 32];
    }
    f32x4 acc = {0.f,0.f,0.f,0.f};
    short8 bs0, bs1;
    #pragma unroll
    for (int dd=0;dd<8;dd++) bs0[dd] = (short)f2bf(st[dd]);
    #pragma unroll
    for (int dd=0;dd<8;dd++) bs1[dd] = (short)f2bf(st[dd+8]);
    acc = MFMA16(aq0, bs0, acc);
    acc = MFMA16(aq1, bs1, acc);
    #pragma unroll
    for (int r=0;r<4;r++){
      int i = w*16 + lg*4 + r;
      size_t oi = obh + (size_t)(c*64 + i)*2048;
      o[oi] = f2bf(bf2f(o[oi]) + dqv[r]*acc[r]);
    }
    #pragma unroll
    for (int i2=0;i2<8;i2++) st[i2]   = gC*st[i2]   + bf2f((u16)sc0[i2]);
    #pragma unroll
    for (int i2=0;i2<8;i2++) st[i2+8] = gC*st[i2+8] + bf2f((u16)sc1[i2]);
  }
}

// ---------------- fused RMSNorm (over DV=128) + swish gate -> bf16 ----------------
// Vectorized (G13): 16 lanes per (row,head), short8 (16B) loads,
// 8 elems/thread, shfl_xor 8/4/2/1 reduction within aligned 16-lane groups.
__global__ __launch_bounds__(256) void norm_gate(const u16* __restrict__ o,
    const u16* __restrict__ qkvg, const float* __restrict__ gnw, u16* __restrict__ og){
  int g16 = threadIdx.x >> 4;          // 16 groups per block
  int l16 = threadIdx.x & 15;          // lane within group
  int rowh = blockIdx.x*16 + g16;
  int row = rowh >> 4, h = rowh & 15;
  short8 vv = *(const short8*)(o + (size_t)row*2048 + h*128 + l16*8);
  float v[8];
  float ss = 0.f;
  #pragma unroll
  for (int j=0;j<8;j++){ v[j] = bf2f((u16)vv[j]); ss += v[j]*v[j]; }
  #pragma unroll
  for (int off=8; off; off>>=1) ss += __shfl_xor(ss, off);
  float rs = rsqrtf(ss*(1.0f/128.0f) + 1e-5f);
  short8 gg = *(const short8*)(qkvg + (size_t)row*6144 + 4096 + h*128 + l16*8);
  float4 w0 = *(const float4*)&gnw[l16*8];
  float4 w1 = *(const float4*)&gnw[l16*8 + 4];
  float wv[8] = {w0.x,w0.y,w0.z,w0.w,w1.x,w1.y,w1.z,w1.w};
  short8 res;
  #pragma unroll
  for (int j=0;j<8;j++){
    float gj = bf2f((u16)gg[j]);
    float rj = v[j]*rs*wv[j] * (gj/(1.f+expf(-gj)));
    res[j] = (short)f2bf(rj);
  }
  *(short8*)(og + (size_t)row*2048 + h*128 + l16*8) = res;
}

extern "C" void kernel_launch(void* const* d_in, const int* in_sizes, int n_in,
                              void* d_out, int out_size, void* d_ws, size_t ws_size,
                              hipStream_t stream){
  const float* x   = (const float*)d_in[0];
  const float* Wq  = (const float*)d_in[1];
  const float* Wk  = (const float*)d_in[2];
  const float* Wv  = (const float*)d_in[3];
  const float* Wg  = (const float*)d_in[4];
  const float* Wo  = (const float*)d_in[5];
  const float* gnw = (const float*)d_in[6];
  float* out = (float*)d_out;

  const size_t NEED = 171966464ull;    // 164 MB
  if (ws_size < NEED) return;

  char* base = (char*)d_ws;
  u16* qkvg  = (u16*)(base);                 // [8192][6144] bf16            [0,96M)
  u16* obuf  = (u16*)(base + 100663296);     // [8192][2048] bf16            [96M,128M)
  u16* WoT   = (u16*)(base + 134217728);     // [1024][2048] bf16            [128M,132M)
  u16* xb    = (u16*)(base + 138412032);     // [8192][1024] bf16            dead after gemm1
  u16* WcatT = (u16*)(base + 155189248);     // [6144][1024] bf16            dead after gemm1
  u16* stt   = (u16*)(base + 138412032);     // [B][H][64][128][64] bf16     alias, live r1->r2
  u16* og    = (u16*)(base + 138412032);     // [8192][2048] bf16            alias, live ng->gemm2

  prep<<<16384,256,0,stream>>>(x, xb, Wq, Wk, Wv, Wg, Wo, WcatT, WoT);
  gemm1_256<<<dim3(24,32),512,0,stream>>>(xb, WcatT, qkvg);
  retention_r1<<<2048,256,0,stream>>>(qkvg, obuf, stt);
  retention_r2<<<256,256,0,stream>>>(qkvg, stt, obuf);
  norm_gate<<<8192,256,0,stream>>>(obuf, qkvg, gnw, og);
  gemm2_nt<<<dim3(8,64),256,0,stream>>>(og, WoT, out, 8192, 1024, 2048);
}

// Round 9
// 282.834 us; speedup vs baseline: 1.1466x; 1.0169x over previous
//
#include <hip/hip_runtime.h>
#include <stdint.h>
#include <type_traits>

typedef unsigned short u16;
typedef __attribute__((ext_vector_type(8))) short short8;
typedef __attribute__((ext_vector_type(4))) float f32x4;

#define MFMA16(a,b,c) __builtin_amdgcn_mfma_f32_16x16x32_bf16(a,b,c,0,0,0)

__device__ __forceinline__ u16 f2bf(float f){
  uint32_t u = __builtin_bit_cast(uint32_t, f);
  u += 0x7FFFu + ((u>>16)&1u);
  return (u16)(u>>16);
}
__device__ __forceinline__ float bf2f(u16 h){
  uint32_t u = ((uint32_t)h)<<16;
  return __builtin_bit_cast(float, u);
}

// ---------------- prep: cast x f32->bf16 (bid<8192) + all weight transposes ----------------
__global__ __launch_bounds__(256) void prep(const float* __restrict__ x, u16* __restrict__ xb,
    const float* __restrict__ Wq, const float* __restrict__ Wk, const float* __restrict__ Wv,
    const float* __restrict__ Wg, const float* __restrict__ Wo,
    u16* __restrict__ WcatT, u16* __restrict__ WoT){
  int bid = blockIdx.x;
  if (bid < 8192){
    int i = (bid*256 + threadIdx.x)*4;
    float4 v = *(const float4*)&x[i];
    uint2 u;
    u.x = (uint32_t)f2bf(v.x) | ((uint32_t)f2bf(v.y)<<16);
    u.y = (uint32_t)f2bf(v.z) | ((uint32_t)f2bf(v.w)<<16);
    *(uint2*)&xb[i] = u;
    return;
  }
  bid -= 8192;
  const float* src; u16* dst; int R, Cc, tc, tr;
  if (bid < 1024){        src=Wq; dst=WcatT;             R=1024; Cc=1024; int b=bid;      tc=(b&31)*32; tr=(b>>5)*32; }
  else if (bid < 2048){   src=Wk; dst=WcatT+1024*1024;   R=1024; Cc=1024; int b=bid-1024; tc=(b&31)*32; tr=(b>>5)*32; }
  else if (bid < 4096){   src=Wv; dst=WcatT+2048*1024;   R=1024; Cc=2048; int b=bid-2048; tc=(b&63)*32; tr=(b>>6)*32; }
  else if (bid < 6144){   src=Wg; dst=WcatT+4096*1024;   R=1024; Cc=2048; int b=bid-4096; tc=(b&63)*32; tr=(b>>6)*32; }
  else {                  src=Wo; dst=WoT;               R=2048; Cc=1024; int b=bid-6144; tc=(b&31)*32; tr=(b>>5)*32; }
  __shared__ float tile[32][33];
  int lr = threadIdx.x>>5, lc = threadIdx.x&31;
  #pragma unroll
  for (int p=0;p<4;p++)
    tile[lr+p*8][lc] = src[(size_t)(tr+lr+p*8)*Cc + tc + lc];
  __syncthreads();
  #pragma unroll
  for (int p=0;p<4;p++)
    dst[(size_t)(tc+lr+p*8)*R + tr + lc] = f2bf(tile[lc][lr+p*8]);
}

// =================================================================
// gemm1: UNCHANGED from round 8 (156us, best). Serves as sentinel for
// environmental drift this round. 2-phase read-ahead, 1 barrier/kt,
// XCD swizzle, fused RoPE epilogue.
// =================================================================
__global__ __launch_bounds__(512,1) void gemm1_256(const u16* __restrict__ A,
    const u16* __restrict__ BT, u16* __restrict__ C){
  __shared__ u16 L[4*16384];          // 4 x (A 8192 | B 8192) u16 = 128 KiB
  const int flat = blockIdx.y*24 + blockIdx.x;   // grid (24,32) = 768
  const int xcd  = flat & 7, loc = flat >> 3;    // loc in [0,96)
  const int bm   = xcd*4 + (loc & 3);            // [0,32): 4 A-panels per XCD, L2-resident
  const int bn   = loc >> 2;                     // [0,24): B streams
  const int t = threadIdx.x;          // 0..511
  const int w = t>>6, l = t&63;
  const int wm = w>>2, wn = w&3;      // 2M x 4N waves
  const int lr = l&15, lg = l>>4;
  const int srow = t>>2;              // 0..127 staging row within half
  const int gsw = ((t&3) - (t>>3)) & 3;   // inverse-swizzled source granule
  const size_t aoff = (size_t)(bm*256 + srow)*1024 + gsw*8;
  const size_t boff = (size_t)(bn*256 + srow)*1024 + gsw*8;
  const int sdo = t*8;

  u16 *p0 = L, *p1 = L+16384, *p2 = L+32768, *p3 = L+49152;

  auto STAGE = [&](u16* buf, int k0){
    __builtin_amdgcn_global_load_lds(&A[aoff + k0],                     buf + sdo,               16,0,0);
    __builtin_amdgcn_global_load_lds(&A[aoff + (size_t)128*1024 + k0],  buf + sdo + 4096,        16,0,0);
    __builtin_amdgcn_global_load_lds(&BT[boff + k0],                    buf + 8192 + sdo,        16,0,0);
    __builtin_amdgcn_global_load_lds(&BT[boff + (size_t)128*1024 + k0], buf + 8192 + sdo + 4096, 16,0,0);
  };
  auto LDA = [&](const u16* base, int row)->short8 {
    return *(const short8*)(base + row*32 + (((lg + (row>>1))&3)<<3));
  };

  f32x4 acc[8][4];
  #pragma unroll
  for (int m=0;m<8;m++)
    #pragma unroll
    for (int n=0;n<4;n++) acc[m][n] = (f32x4){0.f,0.f,0.f,0.f};

  STAGE(p0, 0); STAGE(p1, 32); STAGE(p2, 64);
  asm volatile("s_waitcnt vmcnt(8)" ::: "memory");
  __builtin_amdgcn_s_barrier();
  short8 afA[4], afB[4], bf4[4], bf4n[4];
  #pragma unroll
  for (int m=0;m<4;m++) afA[m] = LDA(p0, wm*128 + m*16 + lr);
  #pragma unroll
  for (int n=0;n<4;n++) bf4[n] = LDA(p0 + 8192, wn*64 + n*16 + lr);

  for (int kt=0; kt<32; ++kt){
    #pragma unroll
    for (int m=0;m<4;m++) afB[m] = LDA(p0, wm*128 + (m+4)*16 + lr);
    if (kt+3 < 32) STAGE(p3, (kt+3)*32);
    __builtin_amdgcn_s_setprio(1);
    #pragma unroll
    for (int m=0;m<4;m++)
      #pragma unroll
      for (int n=0;n<4;n++)
        acc[m][n] = MFMA16(afA[m], bf4[n], acc[m][n]);
    __builtin_amdgcn_s_setprio(0);
    asm volatile("s_waitcnt lgkmcnt(0)" ::: "memory");
    __builtin_amdgcn_sched_barrier(0);
    if      (kt < 29)  asm volatile("s_waitcnt vmcnt(8)" ::: "memory");
    else if (kt == 29) asm volatile("s_waitcnt vmcnt(4)" ::: "memory");
    else               asm volatile("s_waitcnt vmcnt(0)" ::: "memory");
    __builtin_amdgcn_s_barrier();
    __builtin_amdgcn_sched_barrier(0);
    if (kt+1 < 32){
      #pragma unroll
      for (int m=0;m<4;m++) afA[m]  = LDA(p1, wm*128 + m*16 + lr);
      #pragma unroll
      for (int n=0;n<4;n++) bf4n[n] = LDA(p1 + 8192, wn*64 + n*16 + lr);
    }
    __builtin_amdgcn_s_setprio(1);
    #pragma unroll
    for (int m=0;m<4;m++)
      #pragma unroll
      for (int n=0;n<4;n++)
        acc[m+4][n] = MFMA16(afB[m], bf4[n], acc[m+4][n]);
    __builtin_amdgcn_s_setprio(0);
    if (kt+1 < 32){
      #pragma unroll
      for (int n=0;n<4;n++) bf4[n] = bf4n[n];
    }
    { u16* tp=p0; p0=p1; p1=p2; p2=p3; p3=tp; }
  }

  // ---- epilogue: LDS repack in 4 slabs of 64 rows, fused RoPE on q/k ----
  __syncthreads();
  const bool qk = (bn < 8);
  const float qscale = (bn < 4) ? 0.125f : 1.0f;   // DK^-0.5 folded into q
  #pragma unroll
  for (int s=0;s<4;++s){
    if (wm == (s>>1)){
      #pragma unroll
      for (int mm=0;mm<4;++mm){
        const int m = (s&1)*4 + mm;
        if (qk){
          #pragma unroll
          for (int n=0;n<2;n++){
            float inv = exp2f((float)(n*16+lr) * (-13.287712379549449f/32.0f)); // 10000^(-i/32)
            #pragma unroll
            for (int r=0;r<4;r++){
              int grow = bm*256 + wm*128 + m*16 + lg*4 + r;
              float f = (float)(grow & 4095) * inv;
              float sn, cs; __sincosf(f, &sn, &cs);
              float x1 = acc[m][n][r], x2 = acc[m][n+2][r];
              int lrow = mm*16 + lg*4 + r;
              L[lrow*264 + wn*64 + n*16 + lr]     = f2bf((x1*cs - x2*sn)*qscale);
              L[lrow*264 + wn*64 + (n+2)*16 + lr] = f2bf((x1*sn + x2*cs)*qscale);
            }
          }
        } else {
          #pragma unroll
          for (int n=0;n<4;n++)
            #pragma unroll
            for (int r=0;r<4;r++)
              L[(mm*16+lg*4+r)*264 + wn*64 + n*16 + lr] = f2bf(acc[m][n][r]);
        }
      }
    }
    __syncthreads();
    #pragma unroll
    for (int p=0;p<4;p++){
      int idx = p*512 + t;
      int row = idx>>5, gr = idx&31;
      *(short8*)&C[(size_t)(bm*256 + s*64 + row)*6144 + bn*256 + gr*8] =
        *(const short8*)&L[row*264 + gr*8];
    }
    __syncthreads();
  }
}

// ---------------- NT GEMM (gemm2): round-9 2-phase read-ahead port ----------------
// Same schedule class as gemm1 r8: phase A reads af23(kt) under MFMA m0,1;
// phase B reads af01/bfr(kt+1) under MFMA m2,3. One barrier/kt, counted
// vmcnt shifted one kt earlier (3-buffer depth-2: 4/0 at NT-2).
__global__ __launch_bounds__(256) void gemm2_nt(const u16* __restrict__ A,
    const u16* __restrict__ BT, float* __restrict__ C, int M, int N, int K){
  __shared__ u16 L[3*8192];
  const int flat = blockIdx.y*gridDim.x + blockIdx.x;
  const int xcd  = flat & 7, loc = flat >> 3;    // loc in [0,64)
  const int bm   = xcd*8 + (loc & 7);            // [0,64)
  const int bn   = loc >> 3;                     // [0,8)
  const int t = threadIdx.x;
  const int w = t>>6, l = t&63;
  const int wr = (w>>1)*64, wc = (w&1)*64;
  const int lr = l&15, lg = l>>4;
  const int srow = t>>2;
  const int gsw  = ((t&3) - (t>>3)) & 3;
  const int scol = gsw*8;
  const size_t aoff = (size_t)(bm*128 + srow)*K + scol;
  const size_t boff = (size_t)(bn*128 + srow)*K + scol;
  const int sdo = t*8;

  u16 *a0 = L,          *b0 = L + 4096;
  u16 *a1 = L + 8192,   *b1 = L + 12288;
  u16 *a2 = L + 16384,  *b2 = L + 20480;

  auto STAGE = [&](u16* la, u16* lb, int k0){
    __builtin_amdgcn_global_load_lds(&A[aoff + k0],                 la + sdo,        16, 0, 0);
    __builtin_amdgcn_global_load_lds(&A[aoff + (size_t)64*K + k0],  la + sdo + 2048, 16, 0, 0);
    __builtin_amdgcn_global_load_lds(&BT[boff + k0],                lb + sdo,        16, 0, 0);
    __builtin_amdgcn_global_load_lds(&BT[boff + (size_t)64*K + k0], lb + sdo + 2048, 16, 0, 0);
  };
  auto LDR = [&](const u16* base, int row)->short8 {
    return *(const short8*)(base + row*32 + (((lg + (row>>1))&3)<<3));
  };

  f32x4 acc[4][4];
  for (int m=0;m<4;m++) for (int n=0;n<4;n++) acc[m][n] = (f32x4){0.f,0.f,0.f,0.f};

  const int NT = K >> 5;
  STAGE(a0, b0, 0);
  STAGE(a1, b1, 32);
  asm volatile("s_waitcnt vmcnt(4)" ::: "memory");   // own buf-0 loads done
  __builtin_amdgcn_s_barrier();                       // all waves' buf-0 done
  short8 af01[2], af23[2], bfr[4], bfrn[4];
  #pragma unroll
  for (int m=0;m<2;m++) af01[m] = LDR(a0, wr + m*16 + lr);
  #pragma unroll
  for (int n=0;n<4;n++) bfr[n] = LDR(b0, wc + n*16 + lr);

  for (int kt=0; kt<NT; ++kt){
    // phase A: read af23(kt) under MFMA m0,1; issue stage kt+2
    #pragma unroll
    for (int m=0;m<2;m++) af23[m] = LDR(a0, wr + (m+2)*16 + lr);
    if (kt+2 < NT) STAGE(a2, b2, (kt+2)*32);
    __builtin_amdgcn_s_setprio(1);
    #pragma unroll
    for (int m=0;m<2;m++)
      #pragma unroll
      for (int n=0;n<4;n++)
        acc[m][n] = MFMA16(af01[m], bfr[n], acc[m][n]);
    __builtin_amdgcn_s_setprio(0);
    asm volatile("s_waitcnt lgkmcnt(0)" ::: "memory");
    __builtin_amdgcn_sched_barrier(0);
    if (kt < NT-2) asm volatile("s_waitcnt vmcnt(4)" ::: "memory");
    else           asm volatile("s_waitcnt vmcnt(0)" ::: "memory");
    __builtin_amdgcn_s_barrier();
    __builtin_amdgcn_sched_barrier(0);
    // phase B: read af01/bfr(kt+1) from a1/b1 under MFMA m2,3
    if (kt+1 < NT){
      #pragma unroll
      for (int m=0;m<2;m++) af01[m] = LDR(a1, wr + m*16 + lr);
      #pragma unroll
      for (int n=0;n<4;n++) bfrn[n] = LDR(b1, wc + n*16 + lr);
    }
    __builtin_amdgcn_s_setprio(1);
    #pragma unroll
    for (int m=0;m<2;m++)
      #pragma unroll
      for (int n=0;n<4;n++)
        acc[m+2][n] = MFMA16(af23[m], bfr[n], acc[m+2][n]);
    __builtin_amdgcn_s_setprio(0);
    if (kt+1 < NT){
      #pragma unroll
      for (int n=0;n<4;n++) bfr[n] = bfrn[n];
    }
    { u16* tp=a0; a0=a1; a1=a2; a2=tp; }
    { u16* tp=b0; b0=b1; b1=b2; b2=tp; }
  }

  #pragma unroll
  for (int m=0;m<4;m++)
    #pragma unroll
    for (int n=0;n<4;n++){
    int row = bm*128 + wr + m*16 + lg*4;
    int col = bn*128 + wc + n*16 + lr;
    #pragma unroll
    for (int r=0;r<4;r++)
      C[(size_t)(row+r)*N + col] = acc[m][n][r];
  }
}

// ---------------- retention pass 1: XOR-granule-swizzled kT/vT, decay table ----------------
__global__ __launch_bounds__(256) void retention_r1(const u16* __restrict__ qkvg,
    u16* __restrict__ o, u16* __restrict__ states){
  int bid = blockIdx.x;                 // ((b*16+h)*64 + c)
  int c = bid & 63, h = (bid>>6)&15, b = bid>>10;
  int t = threadIdx.x, w = t>>6, l = t&63, lr = l&15, lg = l>>4;
  __shared__ u16 SH[17280];             // kT[64][64] | vT[128][64] | A_lds[64][72]; reused by epilogue
  __shared__ float pw[72];              // gamma^delta
  u16* kT    = SH;                      // granule-swizzled: g' = g ^ ((row>>3)&7)
  u16* vT    = SH + 4096;
  u16* A_lds = SH + 12288;              // [64][72] unswizzled
  float log2g = log2f(1.0f - exp2f(-5.0f - (float)h));
  if (t < 65) pw[t] = exp2f(log2g*(float)t);
  const size_t rowbase = (size_t)(b*4096 + c*64);
  __syncthreads();

  // stage + transpose k, v into LDS (paired u32 writes, XOR-granule swizzle)
  {
    int rp = t>>3, cg = t&7;            // k: 32 row-pairs x 8 col-groups
    int r0 = rp*2;
    short8 k0v = *(const short8*)&qkvg[(rowbase+r0  )*6144 + 1024 + h*64 + cg*8];
    short8 k1v = *(const short8*)&qkvg[(rowbase+r0+1)*6144 + 1024 + h*64 + cg*8];
    float d0 = pw[63-r0], d1 = pw[62-r0];
    #pragma unroll
    for (int j=0;j<8;j++){
      int d = cg*8+j;
      uint32_t pk = (uint32_t)f2bf(bf2f((u16)k0v[j])*d0) | ((uint32_t)f2bf(bf2f((u16)k1v[j])*d1)<<16);
      *(uint32_t*)&kT[d*64 + (((r0>>3) ^ (d>>3))<<3) + (r0&7)] = pk;
    }
    #pragma unroll
    for (int p=0;p<2;p++){              // v: 32 row-pairs x 16 col-groups
      int it = t + p*256;
      int vrp = it>>4, vcg = it&15;
      int vr0 = vrp*2;
      short8 v0 = *(const short8*)&qkvg[(rowbase+vr0  )*6144 + 2048 + h*128 + vcg*8];
      short8 v1 = *(const short8*)&qkvg[(rowbase+vr0+1)*6144 + 2048 + h*128 + vcg*8];
      #pragma unroll
      for (int j=0;j<8;j++){
        int e = vcg*8+j;
        uint32_t pv = (uint32_t)(u16)v0[j] | ((uint32_t)(u16)v1[j]<<16);
        *(uint32_t*)&vT[e*64 + (((vr0>>3) ^ ((e>>3)&7))<<3) + (vr0&7)] = pv;
      }
    }
  }

  // A = q @ k^T
  f32x4 z4 = {0.f,0.f,0.f,0.f};
  f32x4 accA[4] = {z4,z4,z4,z4};
  #pragma unroll
  for (int ks=0;ks<2;ks++){
    short8 aq = *(const short8*)&qkvg[(rowbase + w*16+lr)*6144 + h*64 + ks*32 + lg*8];
    #pragma unroll
    for (int n=0;n<4;n++){
      short8 bk = *(const short8*)&qkvg[(rowbase + n*16+lr)*6144 + 1024 + h*64 + ks*32 + lg*8];
      accA[n] = MFMA16(aq, bk, accA[n]);
    }
  }
  #pragma unroll
  for (int n=0;n<4;n++)
    #pragma unroll
    for (int r=0;r<4;r++){
    int i = w*16 + lg*4 + r, j = n*16 + lr;
    float v = (i>=j) ? accA[n][r]*pw[i-j] : 0.0f;
    A_lds[i*72 + j] = f2bf(v);
  }
  __syncthreads();

  // o_intra = A @ v ; S_c = kdT @ v   (swizzled granule reads: broadcast, conflict-free)
  f32x4 accO[8], accS[8];
  #pragma unroll
  for (int n=0;n<8;n++){ accO[n]=z4; accS[n]=z4; }
  #pragma unroll
  for (int ks=0;ks<2;ks++){
    int rk = w*16+lr;
    short8 aA = *(const short8*)&A_lds[rk*72 + ks*32+lg*8];
    short8 aK = *(const short8*)&kT[rk*64 + (((ks*4+lg) ^ (rk>>3))<<3)];
    #pragma unroll
    for (int n=0;n<8;n++){
      int e2 = n*16+lr;
      short8 bv = *(const short8*)&vT[e2*64 + (((ks*4+lg) ^ ((e2>>3)&7))<<3)];
      accO[n] = MFMA16(aA, bv, accO[n]);
      accS[n] = MFMA16(aK, bv, accS[n]);
    }
  }

  // -------- coalesced epilogue: repack via LDS --------
  __syncthreads();
  u16* oB = SH;                          // [64][132]
  u16* sB = SH + 8448;                   // [128][68]
  #pragma unroll
  for (int n=0;n<8;n++)
    #pragma unroll
    for (int r=0;r<4;r++){
    int i = w*16 + lg*4 + r, e = n*16 + lr;
    oB[i*132 + e] = f2bf(accO[n][r]);
    sB[e*68 + i]  = f2bf(accS[n][r]);
  }
  __syncthreads();
  const size_t ob = rowbase*2048 + h*128;
  const size_t sb = ((size_t)(b*16+h)*64 + c)*8192;   // states[b][h][c][e=128][d=64]
  {
    int orow = t>>2, ocol = (t&3)*32;
    #pragma unroll
    for (int q=0;q<4;q++)
      *(short8*)&o[ob + (size_t)orow*2048 + ocol + q*8] = *(const short8*)&oB[orow*132 + ocol + q*8];
    int se = t>>1, sd = (t&1)*32;
    #pragma unroll
    for (int q=0;q<4;q++)
      *(short8*)&states[sb + (size_t)se*64 + sd + q*8] = *(const short8*)&sB[se*68 + sd + q*8];
  }
}

// ---------------- retention pass 2: scan over chunks, o += (q*dq) @ S ----------------
// Round 9: same-XCD vblk grouping. obuf's 64B lines are RMW'd in 32B halves
// by vblk pairs (e0=0/16 etc.); default round-robin put them on DIFFERENT
// XCDs -> cross-XCD false sharing through non-coherent L2s. Remap so all 8
// vblks of one (b,h) land on ONE XCD (bid&7 = XCD assumed round-robin):
// lines stay in one L2, and the 8x-redundant q-row reads become L2 hits.
__global__ __launch_bounds__(256) void retention_r2(const u16* __restrict__ qkvg,
    const u16* __restrict__ states, u16* __restrict__ o){
  int bid = blockIdx.x;
  int xq = bid & 7, qq = bid >> 3;      // xq = XCD slot
  int bh = xq*4 + (qq & 3);             // all 8 vblks of (b,h) share one XCD
  int vblk = qq >> 2;
  int h = bh & 15, b = bh >> 4;
  int t = threadIdx.x, w = t>>6, l = t&63, lr = l&15, lg = l>>4;
  int e0 = vblk*16;
  float log2g = log2f(1.0f - exp2f(-5.0f - (float)h));
  float gC = exp2f(64.0f*log2g);
  float dqv[4];
  #pragma unroll
  for (int r=0;r<4;r++) dqv[r] = exp2f(log2g*(float)(w*16 + lg*4 + r + 1));
  float st[16];
  #pragma unroll
  for (int i=0;i<16;i++) st[i]=0.f;
  const size_t sbase = ((size_t)(b*16+h)*64)*8192 + (size_t)(e0+lr)*64 + lg*8;
  const size_t qb = (size_t)(b*4096)*6144 + h*64 + (size_t)(w*16+lr)*6144 + lg*8;
  const size_t obh = (size_t)(b*4096)*2048 + h*128 + e0 + lr;
  short8 nsc0 = *(const short8*)&states[sbase];
  short8 nsc1 = *(const short8*)&states[sbase + 32];
  short8 naq0 = *(const short8*)&qkvg[qb];
  short8 naq1 = *(const short8*)&qkvg[qb + 32];
  for (int c=0;c<64;c++){
    short8 sc0 = nsc0, sc1 = nsc1, aq0 = naq0, aq1 = naq1;
    if (c < 63){
      nsc0 = *(const short8*)&states[sbase + (size_t)(c+1)*8192];
      nsc1 = *(const short8*)&states[sbase + (size_t)(c+1)*8192 + 32];
      naq0 = *(const short8*)&qkvg[qb + (size_t)(c+1)*64*6144];
      naq1 = *(const short8*)&qkvg[qb + (size_t)(c+1)*64*6144 + 32];
    }
    f32x4 acc = {0.f,0.f,0.f,0.f};
    short8 bs0, bs1;
    #pragma unroll
    for (int dd=0;dd<8;dd++) bs0[dd] = (short)f2bf(st[dd]);
    #pragma unroll
    for (int dd=0;dd<8;dd++) bs1[dd] = (short)f2bf(st[dd+8]);
    acc = MFMA16(aq0, bs0, acc);
    acc = MFMA16(aq1, bs1, acc);
    #pragma unroll
    for (int r=0;r<4;r++){
      int i = w*16 + lg*4 + r;
      size_t oi = obh + (size_t)(c*64 + i)*2048;
      o[oi] = f2bf(bf2f(o[oi]) + dqv[r]*acc[r]);
    }
    #pragma unroll
    for (int i2=0;i2<8;i2++) st[i2]   = gC*st[i2]   + bf2f((u16)sc0[i2]);
    #pragma unroll
    for (int i2=0;i2<8;i2++) st[i2+8] = gC*st[i2+8] + bf2f((u16)sc1[i2]);
  }
}

// ---------------- fused RMSNorm (over DV=128) + swish gate -> bf16 ----------------
// Vectorized (G13): 16 lanes per (row,head), short8 (16B) loads,
// 8 elems/thread, shfl_xor 8/4/2/1 reduction within aligned 16-lane groups.
__global__ __launch_bounds__(256) void norm_gate(const u16* __restrict__ o,
    const u16* __restrict__ qkvg, const float* __restrict__ gnw, u16* __restrict__ og){
  int g16 = threadIdx.x >> 4;          // 16 groups per block
  int l16 = threadIdx.x & 15;          // lane within group
  int rowh = blockIdx.x*16 + g16;
  int row = rowh >> 4, h = rowh & 15;
  short8 vv = *(const short8*)(o + (size_t)row*2048 + h*128 + l16*8);
  float v[8];
  float ss = 0.f;
  #pragma unroll
  for (int j=0;j<8;j++){ v[j] = bf2f((u16)vv[j]); ss += v[j]*v[j]; }
  #pragma unroll
  for (int off=8; off; off>>=1) ss += __shfl_xor(ss, off);
  float rs = rsqrtf(ss*(1.0f/128.0f) + 1e-5f);
  short8 gg = *(const short8*)(qkvg + (size_t)row*6144 + 4096 + h*128 + l16*8);
  float4 w0 = *(const float4*)&gnw[l16*8];
  float4 w1 = *(const float4*)&gnw[l16*8 + 4];
  float wv[8] = {w0.x,w0.y,w0.z,w0.w,w1.x,w1.y,w1.z,w1.w};
  short8 res;
  #pragma unroll
  for (int j=0;j<8;j++){
    float gj = bf2f((u16)gg[j]);
    float rj = v[j]*rs*wv[j] * (gj/(1.f+expf(-gj)));
    res[j] = (short)f2bf(rj);
  }
  *(short8*)(og + (size_t)row*2048 + h*128 + l16*8) = res;
}

extern "C" void kernel_launch(void* const* d_in, const int* in_sizes, int n_in,
                              void* d_out, int out_size, void* d_ws, size_t ws_size,
                              hipStream_t stream){
  const float* x   = (const float*)d_in[0];
  const float* Wq  = (const float*)d_in[1];
  const float* Wk  = (const float*)d_in[2];
  const float* Wv  = (const float*)d_in[3];
  const float* Wg  = (const float*)d_in[4];
  const float* Wo  = (const float*)d_in[5];
  const float* gnw = (const float*)d_in[6];
  float* out = (float*)d_out;

  const size_t NEED = 171966464ull;    // 164 MB
  if (ws_size < NEED) return;

  char* base = (char*)d_ws;
  u16* qkvg  = (u16*)(base);                 // [8192][6144] bf16            [0,96M)
  u16* obuf  = (u16*)(base + 100663296);     // [8192][2048] bf16            [96M,128M)
  u16* WoT   = (u16*)(base + 134217728);     // [1024][2048] bf16            [128M,132M)
  u16* xb    = (u16*)(base + 138412032);     // [8192][1024] bf16            dead after gemm1
  u16* WcatT = (u16*)(base + 155189248);     // [6144][1024] bf16            dead after gemm1
  u16* stt   = (u16*)(base + 138412032);     // [B][H][64][128][64] bf16     alias, live r1->r2
  u16* og    = (u16*)(base + 138412032);     // [8192][2048] bf16            alias, live ng->gemm2

  prep<<<16384,256,0,stream>>>(x, xb, Wq, Wk, Wv, Wg, Wo, WcatT, WoT);
  gemm1_256<<<dim3(24,32),512,0,stream>>>(xb, WcatT, qkvg);
  retention_r1<<<2048,256,0,stream>>>(qkvg, obuf, stt);
  retention_r2<<<256,256,0,stream>>>(qkvg, stt, obuf);
  norm_gate<<<8192,256,0,stream>>>(obuf, qkvg, gnw, og);
  gemm2_nt<<<dim3(8,64),256,0,stream>>>(og, WoT, out, 8192, 1024, 2048);
}